// Round 15
// baseline (179.368 us; speedup 1.0000x reference)
//
#include <hip/hip_runtime.h>
#include <float.h>
#include <math.h>

#define B_ 2
#define C_ 64
#define HW 64
#define M1 62
#define NP (M1*M1)      // 3844
#define WIN 30
#define KK 5
#define NSEL 16
#define HS 128

#define OUT_SCORE_SZ (B_*KK*HS*HS)       // 163840
#define OUT_IDX_OFF  (OUT_SCORE_SZ)
#define OUT_IDX_SZ   (B_*NP*KK)          // 38440
#define OUT_DIFF_OFF (OUT_IDX_OFF+OUT_IDX_SZ)
#define OUT_DIFF_SZ  (B_*KK*C_*HS*HS)    // 10485760

// ws layout in floats
#define WS_XNP 0
#define WS_YNP 8192
#define WS_TOP 16384                      // ints: B_*NP*16 = 123008
#define WS_SV  (16384+123008)             // 139392
#define WS_DSUM (139392+40960)            // 180352
#define WS_XPM  (180352+2460160)          // 2640512
#define XPM_F   (B_*NP*576)               // 4428288 floats
#define WS_YPM  (WS_XPM + XPM_F)          // 7068800
#define WS_YPBF (WS_YPM + XPM_F)          // 11497088 (ushorts: B_*NP*576)
#define WS_XEBF (WS_YPBF + XPM_F/2)       // 13711232 (ushorts: B_*64*64*64)
#define WS_END  (WS_XEBF + 262144)        // 13973376
#define WS_NEED_BYTES ((size_t)WS_END * 4)   // ~55.9 MB

typedef __attribute__((ext_vector_type(8))) short bf16x8;
typedef __attribute__((ext_vector_type(4))) short bf16x4;
typedef __attribute__((ext_vector_type(4))) short s16x4;
typedef __attribute__((ext_vector_type(4))) float f32x4;

__device__ __forceinline__ unsigned short f2bf(float f) {
    union { float f; unsigned int u; } v; v.f = f;
    unsigned int r = (v.u + 0x7FFFu + ((v.u >> 16) & 1u)) >> 16;
    return (unsigned short)r;
}

__device__ __forceinline__ bf16x8 ld_bf8(const short* p) {
    bf16x4 lo = *(const bf16x4*)p;
    bf16x4 hi = *(const bf16x4*)(p + 4);
    bf16x8 r;
    r[0] = lo[0]; r[1] = lo[1]; r[2] = lo[2]; r[3] = lo[3];
    r[4] = hi[0]; r[5] = hi[1]; r[6] = hi[2]; r[7] = hi[3];
    return r;
}

// ---------------- K-1: xe -> pixel-major bf16 copy xebf[b][h][w][c] ---------
__global__ __launch_bounds__(256) void prep_xebf_kernel(const float* __restrict__ xe,
                                                        unsigned int* __restrict__ xebfW) {
    __shared__ float tile[64 * 65];
    const int bid = blockIdx.x;           // b*64 + h
    const int b = bid >> 6, h = bid & 63;
    const int tid = threadIdx.x;
    for (int i = tid; i < 4096; i += 256) {
        int c = i >> 6, w = i & 63;
        tile[c * 65 + w] = xe[(((size_t)b * C_ + c) * HW + h) * HW + w];
    }
    __syncthreads();
    for (int j = tid; j < 2048; j += 256) {
        int w = j >> 5, cp = j & 31;
        unsigned int u = (unsigned int)f2bf(tile[(2 * cp) * 65 + w])
                       | ((unsigned int)f2bf(tile[(2 * cp + 1) * 65 + w]) << 16);
        xebfW[(((size_t)b * HW + h) * HW + w) * 32 + cp] = u;
    }
}

// ---------------- K0: im2patch (f32 patch-major + permuted bf16 y) ----------
__global__ __launch_bounds__(256) void im2patch_kernel(const float* __restrict__ xe,
                                                       const float* __restrict__ ye,
                                                       float* __restrict__ xpm,
                                                       float* __restrict__ ypm,
                                                       unsigned int* __restrict__ ypbfW) {
    __shared__ float rows[64 * 192];
    __shared__ int tabL[576];
    __shared__ int tabP[576];
    const int tid = threadIdx.x;
    const int bid = blockIdx.x;
    const int srcI = bid / (B_ * M1);
    const int rem = bid - srcI * (B_ * M1);
    const int b = rem / M1, r = rem - b * M1;
    const float* src = (srcI ? ye : xe) + (size_t)b * C_ * HW * HW;
    float* dst = (srcI ? ypm : xpm) + (size_t)(b * NP + r * M1) * 576;

    for (int t = tid; t < 576; t += 256) {
        int c = t / 9, p = t - c * 9;
        tabL[t] = c * 192 + (p / 3) * 64 + (p % 3);
        int cj = (t / 144) * 16 + (t & 15), pj = (t % 144) >> 4;   // decode j
        tabP[t] = cj * 192 + (pj / 3) * 64 + (pj % 3);
    }
    for (int i = tid; i < 64 * 192; i += 256) {
        rows[i] = src[(i / 192) * (HW * HW) + r * HW + (i % 192)];
    }
    __syncthreads();

    for (int s = 0; s < M1; s++) {
        float* d = dst + s * 576;
        for (int e = tid; e < 576; e += 256) d[e] = rows[tabL[e] + s];
        if (srcI) {
            unsigned int* yb = ypbfW + (size_t)(b * NP + r * M1 + s) * 288;
            for (int j2 = tid; j2 < 288; j2 += 256) {
                unsigned int u = (unsigned int)f2bf(rows[tabP[2 * j2] + s])
                               | ((unsigned int)f2bf(rows[tabP[2 * j2 + 1] + s]) << 16);
                yb[j2] = u;
            }
        }
    }
}

// ---------------- K1a: numpy-pairwise norms, dense reads from pm ------------
__global__ __launch_bounds__(256) void norm_np_pm_kernel(const float* __restrict__ xpm,
                                                         const float* __restrict__ ypm,
                                                         float* __restrict__ xnp,
                                                         float* __restrict__ ynp) {
    int gid = blockIdx.x * 256 + threadIdx.x;
    if (gid >= 2 * B_ * NP * 8) return;
    int which = gid / (B_ * NP * 8);
    int rem = gid - which * (B_ * NP * 8);
    int patch = rem >> 3, leaf = rem & 7;
    const float* src = (which ? ypm : xpm) + (size_t)patch * 576 + leaf * 72;

    float a8[8];
    #pragma unroll
    for (int i = 0; i < 8; i++) { float v = src[i]; a8[i] = v * v; }
    for (int i0 = 8; i0 < 72; i0 += 8) {
        #pragma unroll
        for (int i = 0; i < 8; i++) { float v = src[i0 + i]; a8[i] += v * v; }
    }
    float t = ((a8[0] + a8[1]) + (a8[2] + a8[3])) + ((a8[4] + a8[5]) + (a8[6] + a8[7]));
    t = t + __shfl_xor(t, 1, 8);
    t = t + __shfl_xor(t, 2, 8);
    t = t + __shfl_xor(t, 4, 8);
    if (leaf == 0) (which ? ynp : xnp)[patch] = t;
}

// ---------------- K1b: fallback norms (scattered) ---------------------------
__global__ __launch_bounds__(256) void norm_np_kernel(const float* __restrict__ xe,
                                                      const float* __restrict__ ye,
                                                      float* __restrict__ xnp,
                                                      float* __restrict__ ynp) {
    __shared__ int tab[576];
    for (int t = threadIdx.x; t < 576; t += 256) {
        int c = t / 9, p = t - c * 9;
        tab[t] = c * (HW * HW) + (p / 3) * HW + (p % 3);
    }
    __syncthreads();

    int gid = blockIdx.x * 256 + threadIdx.x;
    if (gid >= 2 * B_ * NP * 8) return;
    int which = gid / (B_ * NP * 8);
    int rem = gid - which * (B_ * NP * 8);
    int patch = rem >> 3, leaf = rem & 7;
    int b = patch / NP, m = patch - b * NP;
    int r = m / M1, s = m - r * M1;
    const float* src = (which ? ye : xe) + (size_t)b * C_ * HW * HW + r * HW + s;

    int base = leaf * 72;
    float a8[8];
    #pragma unroll
    for (int i = 0; i < 8; i++) { float v = src[tab[base + i]]; a8[i] = v * v; }
    for (int i0 = 8; i0 < 72; i0 += 8) {
        #pragma unroll
        for (int i = 0; i < 8; i++) { float v = src[tab[base + i0 + i]]; a8[i] += v * v; }
    }
    float t = ((a8[0] + a8[1]) + (a8[2] + a8[3])) + ((a8[4] + a8[5]) + (a8[6] + a8[7]));
    t = t + __shfl_xor(t, 1, 8);
    t = t + __shfl_xor(t, 2, 8);
    t = t + __shfl_xor(t, 4, 8);
    if (leaf == 0) (which ? ynp : xnp)[patch] = t;
}

// ---------------- K2: MFMA prescreen, 16 waves, reg-light selection ---------
#define UPC2 40
#define CSTR2 20
#define YSTR2 580
#define ZOFF_SH (16*YSTR2)
#define YS2_OFF 56000
#define XN2_OFF (YS2_OFF + (ZOFF_SH+16)*2)
#define SM2_BYTES (XN2_OFF + 1089*4)

__global__ __launch_bounds__(1024, 4) void gemm_select_kernel(const float* __restrict__ xe,
                                                              const float* __restrict__ ye,
                                                              const unsigned short* __restrict__ ypbf,
                                                              const unsigned short* __restrict__ xebf,
                                                              const float* __restrict__ xnp,
                                                              int* __restrict__ top_ws,
                                                              int use_pm) {
    __shared__ __align__(16) unsigned char smem[SM2_BYTES];
    short* xsS = (short*)smem;
    unsigned int* xsW = (unsigned int*)smem;
    short* ysS = (short*)(smem + YS2_OFF);
    float* xnL = (float*)(smem + XN2_OFF);
    unsigned int* DlU = (unsigned int*)smem;   // overlays xs+ys after MFMA

    const int bid = blockIdx.x;
    const int b  = bid >> 8;
    const int t  = bid & 255;
    const int r0 = (t >> 4) * 4;
    const int s0 = (t & 15) * 4;
    const int u0r = min(max(r0 - 15, 0), 32);
    const int u0c = min(max(s0 - 15, 0), 32);
    const int g0c = min(u0c & ~3, 24);
    const int cofs = u0c - g0c;
    const int tid = threadIdx.x;
    const int l   = tid & 63;
    const int wid = tid >> 6;             // 0..15
    const int lq  = l & 15;
    const int kg  = l >> 4;
    const int kgh = kg >> 1, kgl = kg & 1;

    if (use_pm) {
        for (int u = tid; u < 16 * 144; u += 1024) {
            int q = u / 144, j4 = u - q * 144;
            int rq = min(r0 + (q >> 2), 61), sq = min(s0 + (q & 3), 61);
            s16x4 v = *(const s16x4*)(ypbf + (size_t)(b * NP + rq * M1 + sq) * 576 + j4 * 4);
            *(s16x4*)(ysS + q * YSTR2 + j4 * 4) = v;
        }
    } else {
        for (int u = tid; u < 16 * 576; u += 1024) {
            int q = u / 576, e = u - q * 576;
            int rq = min(r0 + (q >> 2), 61), sq = min(s0 + (q & 3), 61);
            int c = e / 9, p = e - c * 9;
            float v = ye[((b * C_ + c) * HW + rq + p / 3) * HW + sq + p % 3];
            ysS[q * YSTR2 + (c >> 4) * 144 + p * 16 + (c & 15)] = (short)f2bf(v);
        }
    }
    if (tid < 16) ysS[ZOFF_SH + tid] = 0;
    for (int i = tid; i < 1089; i += 1024) {
        int cr = i / 33, cc = i - cr * 33;
        int nr = min(u0r + cr, 61), nc = min(u0c + cc, 61);
        xnL[i] = xnp[b * NP + nr * M1 + nc];
    }

    f32x4 acc[5];
    #pragma unroll
    for (int i = 0; i < 5; i++) acc[i] = (f32x4){0.f, 0.f, 0.f, 0.f};

    const int PI0[4] = {0, 0, 1, 2}, PJ0[4] = {0, 2, 1, 0};
    const int PI1[4] = {0, 1, 1, 2}, PJ1[4] = {1, 0, 2, 1};

    int prb[5], pcb[5];
    #pragma unroll
    for (int i = 0; i < 5; i++) {
        int ci = (wid * 5 + i) * 16 + lq;  // 0..1279
        int cis = min(ci, 1088);
        int cr = cis / 33;
        prb[i] = cr;
        pcb[i] = cis - cr * 33 + cofs;
    }

    for (int chunk = 0; chunk < 4; chunk++) {
        __syncthreads();
        if (use_pm) {
            for (int u = tid; u < 35 * 40 * 4; u += 1024) {
                int pix = u >> 2, q4 = u & 3;
                int row = pix / 40, col = pix - row * 40;
                int gr = min(u0r + row, 63);
                s16x4 v = *(const s16x4*)(xebf + ((((size_t)b * HW + gr) * HW + g0c + col) << 6)
                                          + chunk * 16 + q4 * 4);
                *(s16x4*)(xsS + pix * CSTR2 + q4 * 4) = v;
            }
        } else {
            for (int u = tid; u < 560; u += 1024) {
                int cp = u & 7, rh = u >> 3;
                int row = rh % 35, half = rh / 35;
                int c0 = chunk * 16 + cp * 2;
                int gr = min(u0r + row, 63);
                const float4* pa = (const float4*)(xe + ((size_t)(b * C_ + c0) * HW + gr) * HW + g0c);
                const float4* pb = (const float4*)(xe + ((size_t)(b * C_ + c0 + 1) * HW + gr) * HW + g0c);
                #pragma unroll
                for (int bb = 0; bb < 5; bb++) {
                    int blk = half * 5 + bb;
                    float4 va = pa[blk], vb = pb[blk];
                    int w0 = (row * UPC2 + blk * 4) * (CSTR2 / 2) + cp;
                    xsW[w0     ] = (unsigned)f2bf(va.x) | ((unsigned)f2bf(vb.x) << 16);
                    xsW[w0 + 10] = (unsigned)f2bf(va.y) | ((unsigned)f2bf(vb.y) << 16);
                    xsW[w0 + 20] = (unsigned)f2bf(va.z) | ((unsigned)f2bf(vb.z) << 16);
                    xsW[w0 + 30] = (unsigned)f2bf(va.w) | ((unsigned)f2bf(vb.w) << 16);
                }
            }
        }
        __syncthreads();

        const int aBase = lq * YSTR2 + chunk * 144;
        #pragma unroll
        for (int t4 = 0; t4 < 5; t4++) {
            bf16x8 af;
            int pi, pj;
            if (t4 < 4) {
                int p = 2 * t4 + kgh;
                af = ld_bf8(ysS + aBase + p * 16 + kgl * 8);
                pi = kgh ? PI1[t4] : PI0[t4];
                pj = kgh ? PJ1[t4] : PJ0[t4];
            } else {
                af = ld_bf8(ysS + ((kg < 2) ? (aBase + 8 * 16 + kgl * 8) : (ZOFF_SH + kgl * 8)));
                pi = 2; pj = 2;
            }
            #pragma unroll
            for (int i = 0; i < 5; i++) {
                bf16x8 bf = ld_bf8(xsS + ((prb[i] + pi) * UPC2 + (pcb[i] + pj)) * CSTR2 + kgl * 8);
                acc[i] = __builtin_amdgcn_mfma_f32_16x16x32_bf16(af, bf, acc[i], 0, 0, 0);
            }
        }
    }

    __syncthreads();
    // epilogue: pack sortable truncated key | ci directly into LDS
    #pragma unroll
    for (int i = 0; i < 5; i++) {
        int ci = (wid * 5 + i) * 16 + lq;
        if (ci < 1089) {
            float xnv = xnL[ci];
            #pragma unroll
            for (int j = 0; j < 4; j++) {
                float v = xnv - 2.0f * acc[i][j];
                unsigned int u = __float_as_uint(v);
                u ^= (unsigned int)((int)u >> 31) | 0x80000000u;
                DlU[(kg * 4 + j) * 1089 + ci] = (u & 0xFFFFF800u) | (unsigned int)ci;
            }
        }
    }
    __syncthreads();

    // selection: one query per wave; lane owns 15 contiguous window slots;
    // running-min in a single register, winner lane rescans from LDS.
    {
        int q = wid;
        int rq = r0 + (q >> 2), sq = s0 + (q & 3);
        if (rq <= 61 && sq <= 61) {
            int siq = min(max(rq - 15, 0), 32);
            int sjq = min(max(sq - 15, 0), 32);
            int ro = siq - u0r, co = sjq - u0c;
            unsigned int* Dq = DlU + q * 1089;
            const int active = (l < 60);
            const int wi2 = l >> 1, wj0 = (l & 1) * 15;
            const int cbase = (ro + wi2) * 33 + (co + wj0);
            unsigned int myMin = 0xFFFFFFFFu;
            if (active) {
                #pragma unroll
                for (int kk = 0; kk < 15; kk++)
                    myMin = min(myMin, Dq[cbase + kk]);
            }
            int obase = (b * NP + rq * M1 + sq) * NSEL;
            for (int it = 0; it < NSEL; it++) {
                unsigned int lm = myMin;
                #pragma unroll
                for (int off = 32; off >= 1; off >>= 1)
                    lm = min(lm, (unsigned int)__shfl_xor((int)lm, off));
                if (l == 0) {
                    int ci = (int)(lm & 2047u);
                    int cr = ci / 33, cc = ci - cr * 33;
                    top_ws[obase + it] = (u0r + cr) * M1 + (u0c + cc);
                }
                if (active && myMin == lm) {
                    int wk = (int)(lm & 2047u) - cbase;
                    Dq[cbase + wk] = 0xFFFFFFFFu;
                    myMin = 0xFFFFFFFFu;
                    #pragma unroll
                    for (int kk = 0; kk < 15; kk++)
                        myMin = min(myMin, Dq[cbase + kk]);
                }
            }
        }
    }
}

// ---------------- K3a: emu from patch-major buffers (dense reads) -----------
__global__ __launch_bounds__(256) void emu_pm_kernel(const float* __restrict__ xpm,
                                                     const float* __restrict__ ypm,
                                                     const float* __restrict__ xnp,
                                                     const float* __restrict__ ynp,
                                                     const int* __restrict__ top_ws,
                                                     float* __restrict__ out_idx,
                                                     float* __restrict__ sv_ws,
                                                     float* __restrict__ dsum_ws) {
    __shared__ float ysE[576];
    __shared__ int topWs[NSEL];
    __shared__ float keyEmu[NSEL];
    __shared__ float selKey[KK];
    __shared__ int   selN[KK];

    const int bid0 = blockIdx.x;
    const int bid = (bid0 & 7) * (B_ * NP / 8) + (bid0 >> 3);  // XCD-affine
    const int b = bid / NP, m = bid - b * NP;
    const int tid = threadIdx.x;
    const float* ybase = ypm + (size_t)(b * NP + m) * 576;

    for (int t = tid; t < 576; t += 256) ysE[t] = ybase[t];
    if (tid < NSEL) topWs[tid] = top_ws[bid * NSEL + tid];
    __syncthreads();

    {
        const int cand = tid >> 4, j = tid & 15;
        const float* xp = xpm + (size_t)(b * NP + topWs[cand]) * 576;
        float acc = 0.f;
        #pragma unroll
        for (int t = 0; t < 36; t++) {
            int e = t * 16 + j;
            acc = fmaf(ysE[e], xp[e], acc);
        }
        float E = acc;
        E = E + __shfl_xor(E, 8, 16);
        E = E + __shfl_xor(E, 4, 16);
        E = E + __shfl_xor(E, 2, 16);
        E = E + __shfl_xor(E, 1, 16);
        if (j == 0) {
            float t0 = -2.0f * E;
            float k1 = t0 + ynp[b * NP + m];
            float k2 = k1 + xnp[b * NP + topWs[cand]];
            keyEmu[cand] = k2 + 1e-5f;
        }
    }
    __syncthreads();

    if (tid == 0) {
        float d[NSEL]; int w[NSEL];
        for (int i = 0; i < NSEL; i++) { d[i] = keyEmu[i]; w[i] = topWs[i]; }
        for (int a = 1; a < NSEL; a++) {
            float dv = d[a]; int wv2 = w[a]; int p = a - 1;
            while (p >= 0 && (d[p] > dv || (d[p] == dv && w[p] > wv2))) {
                d[p + 1] = d[p]; w[p + 1] = w[p]; p--;
            }
            d[p + 1] = dv; w[p + 1] = wv2;
        }
        for (int i = 0; i < KK; i++) { selKey[i] = d[i]; selN[i] = w[i]; }
    }
    __syncthreads();

    if (tid < KK) {
        out_idx[(b * NP + m) * KK + tid] = (float)selN[tid];
        float s10 = selKey[tid] / 10.0f;
        double sv = exp(-(double)s10);
        sv_ws[(b * KK + tid) * NP + m] = (float)sv;
    }

    for (int pair = tid; pair < KK * C_; pair += 256) {
        int k = pair >> 6, c = pair & 63;
        const float* xrow = xpm + (size_t)(b * NP + selN[k]) * 576 + c * 9;
        const float* yrow = ysE + c * 9;
        float a = 0.f;
        #pragma unroll
        for (int p = 0; p < 9; p++) a += fabsf(yrow[p] - xrow[p]);
        dsum_ws[((b * KK + k) * C_ + c) * NP + m] = a;
    }
}

// ---------------- K3b: fallback emu (scattered) ------------------------------
#define XCSTR 584

__global__ __launch_bounds__(256) void emu_fallback_kernel(const float* __restrict__ xe,
                                                           const float* __restrict__ ye,
                                                           const float* __restrict__ xnp,
                                                           const float* __restrict__ ynp,
                                                           const int* __restrict__ top_ws,
                                                           float* __restrict__ out_idx,
                                                           float* __restrict__ sv_ws,
                                                           float* __restrict__ dsum_ws) {
    __shared__ float ysE[576];
    __shared__ int tab[576];
    __shared__ float xc[NSEL * XCSTR];
    __shared__ int topWs[NSEL];
    __shared__ float keyEmu[NSEL];
    __shared__ float selKey[KK];
    __shared__ int   selN[KK];
    __shared__ int   selI[KK];

    const int bid0 = blockIdx.x;
    const int bid = (bid0 & 7) * (B_ * NP / 8) + (bid0 >> 3);
    const int b = bid / NP, m = bid - b * NP;
    const int r = m / M1, s = m - r * M1;
    const int tid = threadIdx.x;
    const float* xb = xe + (size_t)b * C_ * HW * HW;
    const float* yb = ye + (size_t)b * C_ * HW * HW + r * HW + s;

    for (int t = tid; t < 576; t += 256) {
        int c = t / 9, p = t - c * 9;
        tab[t] = c * (HW * HW) + (p / 3) * HW + (p % 3);
    }
    if (tid < NSEL) topWs[tid] = top_ws[bid * NSEL + tid];
    __syncthreads();

    for (int t = tid; t < 576; t += 256) ysE[t] = yb[tab[t]];
    for (int i = tid; i < NSEL * 576; i += 256) {
        int cand = i / 576, e = i - cand * 576;
        int n = topWs[cand];
        int px = n / M1, py = n - px * M1;
        xc[cand * XCSTR + e] = xb[px * HW + py + tab[e]];
    }
    __syncthreads();

    {
        const int cand = tid >> 4, j = tid & 15;
        const float* xcp = xc + cand * XCSTR;
        float acc = 0.f;
        #pragma unroll
        for (int t = 0; t < 36; t++) {
            int e = t * 16 + j;
            acc = fmaf(ysE[e], xcp[e], acc);
        }
        float E = acc;
        E = E + __shfl_xor(E, 8, 16);
        E = E + __shfl_xor(E, 4, 16);
        E = E + __shfl_xor(E, 2, 16);
        E = E + __shfl_xor(E, 1, 16);
        if (j == 0) {
            float t0 = -2.0f * E;
            float k1 = t0 + ynp[b * NP + m];
            float k2 = k1 + xnp[b * NP + topWs[cand]];
            keyEmu[cand] = k2 + 1e-5f;
        }
    }
    __syncthreads();

    if (tid == 0) {
        float d[NSEL]; int w[NSEL]; int ix[NSEL];
        for (int i = 0; i < NSEL; i++) { d[i] = keyEmu[i]; w[i] = topWs[i]; ix[i] = i; }
        for (int a = 1; a < NSEL; a++) {
            float dv = d[a]; int wv2 = w[a]; int iv = ix[a]; int p = a - 1;
            while (p >= 0 && (d[p] > dv || (d[p] == dv && w[p] > wv2))) {
                d[p + 1] = d[p]; w[p + 1] = w[p]; ix[p + 1] = ix[p]; p--;
            }
            d[p + 1] = dv; w[p + 1] = wv2; ix[p + 1] = iv;
        }
        for (int i = 0; i < KK; i++) { selKey[i] = d[i]; selN[i] = w[i]; selI[i] = ix[i]; }
    }
    __syncthreads();

    if (tid < KK) {
        out_idx[(b * NP + m) * KK + tid] = (float)selN[tid];
        float s10 = selKey[tid] / 10.0f;
        double sv = exp(-(double)s10);
        sv_ws[(b * KK + tid) * NP + m] = (float)sv;
    }

    for (int pair = tid; pair < KK * C_; pair += 256) {
        int k = pair >> 6, c = pair & 63;
        const float* xcp = xc + selI[k] * XCSTR + c * 9;
        const float* ycp = ysE + c * 9;
        float a = 0.f;
        #pragma unroll
        for (int p = 0; p < 9; p++) a += fabsf(ycp[p] - xcp[p]);
        dsum_ws[((b * KK + k) * C_ + c) * NP + m] = a;
    }
}

// ---------------- overlap-add image kernels ---------------------------------
__device__ __forceinline__ void oa_range(int y, int& r0, int& r1) {
    r0 = (y >= 5) ? ((y - 4) >> 1) : 0;
    r1 = min(M1 - 1, y >> 1);
}

__global__ __launch_bounds__(256) void score_img_kernel(const float* __restrict__ sv_ws,
                                                        float* __restrict__ out) {
    int idx = blockIdx.x * 256 + threadIdx.x;
    if (idx >= OUT_SCORE_SZ) return;
    int x = idx & 127, y = (idx >> 7) & 127;
    int bk = idx >> 14;
    int r0, r1, s0, s1;
    oa_range(y, r0, r1);
    oa_range(x, s0, s1);
    const float* base = sv_ws + bk * NP;
    float acc = 0.f;
    for (int rr = r0; rr <= r1; rr++)
        for (int ss = s0; ss <= s1; ss++)
            acc += base[rr * M1 + ss];
    out[idx] = acc;
}

// separable per-plane overlap-add: row pass into LDS, then col pass.
__global__ __launch_bounds__(256) void diff_img_sep_kernel(const float* __restrict__ dsum_ws,
                                                           float* __restrict__ out) {
    __shared__ float dpl[NP];             // 62*62 = 15.4KB
    __shared__ float trow[M1 * HS];       // 62*128 = 31.7KB
    const int bkc = blockIdx.x;           // [0,640)
    const int tid = threadIdx.x;
    const float* src = dsum_ws + (size_t)bkc * NP;

    for (int i = tid; i < NP; i += 256) dpl[i] = src[i];
    __syncthreads();

    for (int u = tid; u < M1 * HS; u += 256) {
        int rr = u >> 7, x = u & 127;
        int s0, s1;
        oa_range(x, s0, s1);
        const float* dr = dpl + rr * M1;
        float a = 0.f;
        for (int ss = s0; ss <= s1; ss++) a += dr[ss];
        trow[rr * HS + x] = a;
    }
    __syncthreads();

    float* dst = out + (size_t)bkc * (HS * HS);
    for (int u = tid; u < HS * HS; u += 256) {
        int y = u >> 7, x = u & 127;
        int r0, r1;
        oa_range(y, r0, r1);
        float a = 0.f;
        for (int rr = r0; rr <= r1; rr++) a += trow[rr * HS + x];
        dst[u] = a;
    }
}

extern "C" void kernel_launch(void* const* d_in, const int* in_sizes, int n_in,
                              void* d_out, int out_size, void* d_ws, size_t ws_size,
                              hipStream_t stream) {
    const float* xe = (const float*)d_in[0];
    const float* ye = (const float*)d_in[1];
    float* out = (float*)d_out;
    float* ws = (float*)d_ws;

    float* xnp = ws + WS_XNP;
    float* ynp = ws + WS_YNP;
    int*   topw = (int*)(ws + WS_TOP);
    float* sv_ws = ws + WS_SV;
    float* dsum_ws = ws + WS_DSUM;
    float* xpm = ws + WS_XPM;
    float* ypm = ws + WS_YPM;
    unsigned int* ypbfW = (unsigned int*)(ws + WS_YPBF);
    unsigned int* xebfW = (unsigned int*)(ws + WS_XEBF);

    const bool pm_ok = (ws_size >= WS_NEED_BYTES);

    if (pm_ok) {
        prep_xebf_kernel<<<B_ * HW, 256, 0, stream>>>(xe, xebfW);
        im2patch_kernel<<<2 * B_ * M1, 256, 0, stream>>>(xe, ye, xpm, ypm, ypbfW);
        norm_np_pm_kernel<<<(2 * B_ * NP * 8 + 255) / 256, 256, 0, stream>>>(xpm, ypm, xnp, ynp);
    } else {
        norm_np_kernel<<<(2 * B_ * NP * 8 + 255) / 256, 256, 0, stream>>>(xe, ye, xnp, ynp);
    }
    gemm_select_kernel<<<2 * 256, 1024, 0, stream>>>(xe, ye,
                                                     (const unsigned short*)ypbfW,
                                                     (const unsigned short*)xebfW,
                                                     xnp, topw, pm_ok ? 1 : 0);
    if (pm_ok) {
        emu_pm_kernel<<<B_ * NP, 256, 0, stream>>>(xpm, ypm, xnp, ynp, topw,
                                                   out + OUT_IDX_OFF, sv_ws, dsum_ws);
    } else {
        emu_fallback_kernel<<<B_ * NP, 256, 0, stream>>>(xe, ye, xnp, ynp, topw,
                                                         out + OUT_IDX_OFF, sv_ws, dsum_ws);
    }
    score_img_kernel<<<OUT_SCORE_SZ / 256, 256, 0, stream>>>(sv_ws, out);
    diff_img_sep_kernel<<<B_ * KK * C_, 256, 0, stream>>>(dsum_ws, out + OUT_DIFF_OFF);
}

// Round 17
// 148.484 us; speedup vs baseline: 1.2080x; 1.2080x over previous
//
#include <hip/hip_runtime.h>
#include <float.h>
#include <math.h>

#define B_ 2
#define C_ 64
#define HW 64
#define M1 62
#define NP (M1*M1)      // 3844
#define WIN 30
#define KK 5
#define NSEL 16
#define HS 128

#define OUT_SCORE_SZ (B_*KK*HS*HS)       // 163840
#define OUT_IDX_OFF  (OUT_SCORE_SZ)
#define OUT_IDX_SZ   (B_*NP*KK)          // 38440
#define OUT_DIFF_OFF (OUT_IDX_OFF+OUT_IDX_SZ)
#define OUT_DIFF_SZ  (B_*KK*C_*HS*HS)    // 10485760

// ws layout in floats
#define WS_XNP 0
#define WS_YNP 8192
#define WS_TOP 16384                      // ints: B_*NP*16 = 123008
#define WS_SV  (16384+123008)             // 139392
#define WS_DSUM (139392+40960)            // 180352
#define WS_XPM  (180352+2460160)          // 2640512
#define XPM_F   (B_*NP*576)               // 4428288 floats
#define WS_YPM  (WS_XPM + XPM_F)          // 7068800
#define WS_YPBF (WS_YPM + XPM_F)          // 11497088 (ushorts: B_*NP*576)
#define WS_XEBF (WS_YPBF + XPM_F/2)       // 13711232 (ushorts: B_*64*64*64)
#define WS_END  (WS_XEBF + 262144)        // 13973376
#define WS_NEED_BYTES ((size_t)WS_END * 4)   // ~55.9 MB

typedef __attribute__((ext_vector_type(8))) short bf16x8;
typedef __attribute__((ext_vector_type(4))) short bf16x4;
typedef __attribute__((ext_vector_type(4))) short s16x4;
typedef __attribute__((ext_vector_type(4))) float f32x4;
typedef __attribute__((ext_vector_type(16))) float f32x16;

__device__ __forceinline__ unsigned short f2bf(float f) {
    union { float f; unsigned int u; } v; v.f = f;
    unsigned int r = (v.u + 0x7FFFu + ((v.u >> 16) & 1u)) >> 16;
    return (unsigned short)r;
}

__device__ __forceinline__ bf16x8 ld_bf8(const short* p) {
    bf16x4 lo = *(const bf16x4*)p;
    bf16x4 hi = *(const bf16x4*)(p + 4);
    bf16x8 r;
    r[0] = lo[0]; r[1] = lo[1]; r[2] = lo[2]; r[3] = lo[3];
    r[4] = hi[0]; r[5] = hi[1]; r[6] = hi[2]; r[7] = hi[3];
    return r;
}

// ---------------- K0: fused prep (xebf pixel-major bf16 + im2patch) ----------
__global__ __launch_bounds__(256) void prep_fused_kernel(const float* __restrict__ xe,
                                                         const float* __restrict__ ye,
                                                         unsigned int* __restrict__ xebfW,
                                                         float* __restrict__ xpm,
                                                         float* __restrict__ ypm,
                                                         unsigned int* __restrict__ ypbfW) {
    __shared__ __align__(16) unsigned char sm[64 * 192 * 4 + 1152 * 4];
    const int tid = threadIdx.x;
    const int bid = blockIdx.x;

    if (bid < B_ * HW) {
        float* tile = (float*)sm;   // 64*65 floats
        int b = bid >> 6, h = bid & 63;
        for (int i = tid; i < 4096; i += 256) {
            int c = i >> 6, w = i & 63;
            tile[c * 65 + w] = xe[(((size_t)b * C_ + c) * HW + h) * HW + w];
        }
        __syncthreads();
        for (int j = tid; j < 2048; j += 256) {
            int w = j >> 5, cp = j & 31;
            unsigned int u = (unsigned int)f2bf(tile[(2 * cp) * 65 + w])
                           | ((unsigned int)f2bf(tile[(2 * cp + 1) * 65 + w]) << 16);
            xebfW[(((size_t)b * HW + h) * HW + w) * 32 + cp] = u;
        }
    } else {
        int bid2 = bid - B_ * HW;
        float* rows = (float*)sm;                     // 64*192
        int* tabL = (int*)(sm + 64 * 192 * 4);
        int* tabP = tabL + 576;
        const int srcI = bid2 / (B_ * M1);
        const int rem = bid2 - srcI * (B_ * M1);
        const int b = rem / M1, r = rem - b * M1;
        const float* src = (srcI ? ye : xe) + (size_t)b * C_ * HW * HW;
        float* dst = (srcI ? ypm : xpm) + (size_t)(b * NP + r * M1) * 576;

        for (int t = tid; t < 576; t += 256) {
            int c = t / 9, p = t - c * 9;
            tabL[t] = c * 192 + (p / 3) * 64 + (p % 3);
            int cj = (t / 144) * 16 + (t & 15), pj = (t % 144) >> 4;
            tabP[t] = cj * 192 + (pj / 3) * 64 + (pj % 3);
        }
        for (int i = tid; i < 64 * 192; i += 256) {
            rows[i] = src[(i / 192) * (HW * HW) + r * HW + (i % 192)];
        }
        __syncthreads();

        for (int s = 0; s < M1; s++) {
            float* d = dst + s * 576;
            for (int e = tid; e < 576; e += 256) d[e] = rows[tabL[e] + s];
            if (srcI) {
                unsigned int* yb = ypbfW + (size_t)(b * NP + r * M1 + s) * 288;
                for (int j2 = tid; j2 < 288; j2 += 256) {
                    unsigned int u = (unsigned int)f2bf(rows[tabP[2 * j2] + s])
                                   | ((unsigned int)f2bf(rows[tabP[2 * j2 + 1] + s]) << 16);
                    yb[j2] = u;
                }
            }
        }
    }
}

// ---------------- K1a: numpy-pairwise norms, dense reads from pm ------------
__global__ __launch_bounds__(256) void norm_np_pm_kernel(const float* __restrict__ xpm,
                                                         const float* __restrict__ ypm,
                                                         float* __restrict__ xnp,
                                                         float* __restrict__ ynp) {
    int gid = blockIdx.x * 256 + threadIdx.x;
    if (gid >= 2 * B_ * NP * 8) return;
    int which = gid / (B_ * NP * 8);
    int rem = gid - which * (B_ * NP * 8);
    int patch = rem >> 3, leaf = rem & 7;
    const float* src = (which ? ypm : xpm) + (size_t)patch * 576 + leaf * 72;

    float a8[8];
    #pragma unroll
    for (int i = 0; i < 8; i++) { float v = src[i]; a8[i] = v * v; }
    for (int i0 = 8; i0 < 72; i0 += 8) {
        #pragma unroll
        for (int i = 0; i < 8; i++) { float v = src[i0 + i]; a8[i] += v * v; }
    }
    float t = ((a8[0] + a8[1]) + (a8[2] + a8[3])) + ((a8[4] + a8[5]) + (a8[6] + a8[7]));
    t = t + __shfl_xor(t, 1, 8);
    t = t + __shfl_xor(t, 2, 8);
    t = t + __shfl_xor(t, 4, 8);
    if (leaf == 0) (which ? ynp : xnp)[patch] = t;
}

// ---------------- K1b: fallback norms (scattered) ---------------------------
__global__ __launch_bounds__(256) void norm_np_kernel(const float* __restrict__ xe,
                                                      const float* __restrict__ ye,
                                                      float* __restrict__ xnp,
                                                      float* __restrict__ ynp) {
    __shared__ int tab[576];
    for (int t = threadIdx.x; t < 576; t += 256) {
        int c = t / 9, p = t - c * 9;
        tab[t] = c * (HW * HW) + (p / 3) * HW + (p % 3);
    }
    __syncthreads();

    int gid = blockIdx.x * 256 + threadIdx.x;
    if (gid >= 2 * B_ * NP * 8) return;
    int which = gid / (B_ * NP * 8);
    int rem = gid - which * (B_ * NP * 8);
    int patch = rem >> 3, leaf = rem & 7;
    int b = patch / NP, m = patch - b * NP;
    int r = m / M1, s = m - r * M1;
    const float* src = (which ? ye : xe) + (size_t)b * C_ * HW * HW + r * HW + s;

    int base = leaf * 72;
    float a8[8];
    #pragma unroll
    for (int i = 0; i < 8; i++) { float v = src[tab[base + i]]; a8[i] = v * v; }
    for (int i0 = 8; i0 < 72; i0 += 8) {
        #pragma unroll
        for (int i = 0; i < 8; i++) { float v = src[tab[base + i0 + i]]; a8[i] += v * v; }
    }
    float t = ((a8[0] + a8[1]) + (a8[2] + a8[3])) + ((a8[4] + a8[5]) + (a8[6] + a8[7]));
    t = t + __shfl_xor(t, 1, 8);
    t = t + __shfl_xor(t, 2, 8);
    t = t + __shfl_xor(t, 4, 8);
    if (leaf == 0) (which ? ynp : xnp)[patch] = t;
}

// ---------------- K2: 32x32 MFMA prescreen -----------------------------------
// Block = 8x4 query region (32 queries = MFMA M). Union 37x33 (+2 patch) ->
// staged 39x35 pixels, 16 ch/chunk, 48B/pixel. A/B share k = kh*8+idx over 16
// channels of patch-pos p (consistent bijection). C: col=lane&31 (cand),
// row=(reg&3)+8*(reg>>2)+4*(lane>>5) (query) [m74/m101].
#define UROW 39
#define UCOL 35
#define PSTR 24          // shorts per pixel (16 ch + 8 pad) = 48B
#define QSTR 584         // shorts per query y (576 + 8)
#define G_YOFF (UROW*UCOL*PSTR*2)          // 65520
#define G_XNOFF (G_YOFF + 32*QSTR*2)       // 102896
#define G_SM (G_XNOFF + 1280*4)            // 108016

__global__ __launch_bounds__(1024, 4) void gemm32_kernel(const unsigned short* __restrict__ ypbf,
                                                         const unsigned short* __restrict__ xebf,
                                                         const float* __restrict__ xnp,
                                                         int* __restrict__ top_ws) {
    __shared__ __align__(16) unsigned char smem[G_SM];
    short* xs = (short*)smem;
    short* ysS = (short*)(smem + G_YOFF);
    float* xnL = (float*)(smem + G_XNOFF);
    unsigned int* DlU = (unsigned int*)smem;   // overlay xs+ys: 16*1280*4 = 80KB

    const int bid = blockIdx.x;
    const int b = bid >> 7;
    const int t = bid & 127;
    const int r0 = (t >> 4) * 8;
    const int s0 = (t & 15) * 4;
    const int u0r = min(max(r0 - 15, 0), 32);
    const int u0c = min(max(s0 - 15, 0), 32);
    const int tid = threadIdx.x;
    const int l = tid & 63;
    const int w = tid >> 6;               // wave 0..15
    const int lq = l & 31;
    const int kh = l >> 5;                // K-half

    for (int u = tid; u < 32 * 144; u += 1024) {
        int q = u / 144, j4 = u - q * 144;
        int rq = min(r0 + (q >> 2), 61), sq = min(s0 + (q & 3), 61);
        s16x4 v = *(const s16x4*)(ypbf + (size_t)(b * NP + rq * M1 + sq) * 576 + j4 * 4);
        *(s16x4*)(ysS + q * QSTR + j4 * 4) = v;
    }
    for (int i = tid; i < 1221; i += 1024) {
        int cr = i / 33, cc = i - cr * 33;
        int nr = min(u0r + cr, 61), nc = min(u0c + cc, 61);
        xnL[i] = xnp[b * NP + nr * M1 + nc];
    }

    int crA[3], ccA[3];
    #pragma unroll
    for (int t3 = 0; t3 < 3; t3++) {
        int tile = t3 * 16 + w;
        int ci = min(tile * 32 + lq, 1220);
        int cr = ci / 33;
        crA[t3] = cr;
        ccA[t3] = ci - cr * 33;
    }
    const bool v2 = (w < 7);

    f32x16 acc0 = {}, acc1 = {}, acc2 = {};

    for (int chunk = 0; chunk < 4; chunk++) {
        __syncthreads();
        // stage 16-ch chunk (32 BYTES per pixel = 2x int4) of the 39x35 union
        for (int u = tid; u < UROW * UCOL; u += 1024) {
            int rr = u / UCOL, c2 = u - rr * UCOL;
            int gr = min(u0r + rr, 63), gc = min(u0c + c2, 63);
            const unsigned short* sp = xebf + ((((size_t)b * HW + gr) * HW + gc) << 6) + chunk * 16;
            int4 v0 = *(const int4*)sp;
            int4 v1 = *(const int4*)(sp + 8);
            *(int4*)(xs + u * PSTR) = v0;
            *(int4*)(xs + u * PSTR + 8) = v1;
        }
        __syncthreads();

        #pragma unroll
        for (int p = 0; p < 9; p++) {
            const int pi = p / 3, pj = p % 3;
            bf16x8 af = *(const bf16x8*)(ysS + lq * QSTR + chunk * 144 + p * 16 + kh * 8);
            {
                const short* bp = xs + ((crA[0] + pi) * UCOL + (ccA[0] + pj)) * PSTR + kh * 8;
                acc0 = __builtin_amdgcn_mfma_f32_32x32x16_bf16(af, *(const bf16x8*)bp, acc0, 0, 0, 0);
            }
            {
                const short* bp = xs + ((crA[1] + pi) * UCOL + (ccA[1] + pj)) * PSTR + kh * 8;
                acc1 = __builtin_amdgcn_mfma_f32_32x32x16_bf16(af, *(const bf16x8*)bp, acc1, 0, 0, 0);
            }
            if (v2) {
                const short* bp = xs + ((crA[2] + pi) * UCOL + (ccA[2] + pj)) * PSTR + kh * 8;
                acc2 = __builtin_amdgcn_mfma_f32_32x32x16_bf16(af, *(const bf16x8*)bp, acc2, 0, 0, 0);
            }
        }
    }

    for (int ph = 0; ph < 2; ph++) {
        __syncthreads();
        #pragma unroll
        for (int t3 = 0; t3 < 3; t3++) {
            if (t3 == 2 && !v2) continue;
            int ci = (t3 * 16 + w) * 32 + lq;
            if (ci <= 1220) {
                float xnv = xnL[min(ci, 1220)];
                #pragma unroll
                for (int j = 0; j < 8; j++) {
                    int jj = ph * 8 + j;
                    float av = (t3 == 0) ? acc0[jj] : (t3 == 1 ? acc1[jj] : acc2[jj]);
                    int row = (jj & 3) + 8 * (jj >> 2) + 4 * kh;
                    float v = xnv - 2.0f * av;
                    unsigned int u = __float_as_uint(v);
                    u ^= (unsigned int)((int)u >> 31) | 0x80000000u;
                    DlU[(row - ph * 16) * 1280 + ci] = (u & 0xFFFFF800u) | (unsigned int)ci;
                }
            }
        }
        __syncthreads();
        {
            int q = ph * 16 + w;
            int rq = r0 + (q >> 2), sq = s0 + (q & 3);
            if (rq <= 61 && sq <= 61) {
                int siq = min(max(rq - 15, 0), 32);
                int sjq = min(max(sq - 15, 0), 32);
                int ro = siq - u0r, co = sjq - u0c;
                unsigned int* Dq = DlU + w * 1280;
                const int active = (l < 60);
                const int wi2 = l >> 1, wj0 = (l & 1) * 15;
                const int cbase = (ro + wi2) * 33 + (co + wj0);
                unsigned int myMin = 0xFFFFFFFFu;
                if (active) {
                    #pragma unroll
                    for (int kk = 0; kk < 15; kk++) myMin = min(myMin, Dq[cbase + kk]);
                }
                int obase = (b * NP + rq * M1 + sq) * NSEL;
                for (int it = 0; it < NSEL; it++) {
                    unsigned int lm = myMin;
                    #pragma unroll
                    for (int off = 32; off >= 1; off >>= 1)
                        lm = min(lm, (unsigned int)__shfl_xor((int)lm, off));
                    if (l == 0) {
                        int ci = (int)(lm & 2047u);
                        int cr = ci / 33, cc = ci - (ci / 33) * 33;
                        top_ws[obase + it] = (u0r + cr) * M1 + (u0c + cc);
                    }
                    if (active && myMin == lm) {
                        int wk = (int)(lm & 2047u) - cbase;
                        Dq[cbase + wk] = 0xFFFFFFFFu;
                        myMin = 0xFFFFFFFFu;
                        #pragma unroll
                        for (int kk = 0; kk < 15; kk++) myMin = min(myMin, Dq[cbase + kk]);
                    }
                }
            }
        }
    }
}

// ---------------- K2-fb: old 16x16 prescreen (scattered staging) ------------
#define UPC2 40
#define CSTR2 20
#define YSTR2 580
#define ZOFF_SH (16*YSTR2)
#define YS2_OFF 56000
#define XN2_OFF (YS2_OFF + (ZOFF_SH+16)*2)
#define SM2_BYTES (XN2_OFF + 1089*4)

__global__ __launch_bounds__(1024, 4) void gemm_select_fb(const float* __restrict__ xe,
                                                          const float* __restrict__ ye,
                                                          const float* __restrict__ xnp,
                                                          int* __restrict__ top_ws) {
    __shared__ __align__(16) unsigned char smem[SM2_BYTES];
    short* xsS = (short*)smem;
    unsigned int* xsW = (unsigned int*)smem;
    short* ysS = (short*)(smem + YS2_OFF);
    float* xnL = (float*)(smem + XN2_OFF);
    unsigned int* DlU = (unsigned int*)smem;

    const int bid = blockIdx.x;
    const int b  = bid >> 8;
    const int t  = bid & 255;
    const int r0 = (t >> 4) * 4;
    const int s0 = (t & 15) * 4;
    const int u0r = min(max(r0 - 15, 0), 32);
    const int u0c = min(max(s0 - 15, 0), 32);
    const int g0c = min(u0c & ~3, 24);
    const int cofs = u0c - g0c;
    const int tid = threadIdx.x;
    const int l   = tid & 63;
    const int wid = tid >> 6;
    const int lq  = l & 15;
    const int kg  = l >> 4;
    const int kgh = kg >> 1, kgl = kg & 1;

    for (int u = tid; u < 16 * 576; u += 1024) {
        int q = u / 576, e = u - q * 576;
        int rq = min(r0 + (q >> 2), 61), sq = min(s0 + (q & 3), 61);
        int c = e / 9, p = e - c * 9;
        float v = ye[((b * C_ + c) * HW + rq + p / 3) * HW + sq + p % 3];
        ysS[q * YSTR2 + (c >> 4) * 144 + p * 16 + (c & 15)] = (short)f2bf(v);
    }
    if (tid < 16) ysS[ZOFF_SH + tid] = 0;
    for (int i = tid; i < 1089; i += 1024) {
        int cr = i / 33, cc = i - cr * 33;
        int nr = min(u0r + cr, 61), nc = min(u0c + cc, 61);
        xnL[i] = xnp[b * NP + nr * M1 + nc];
    }

    f32x4 acc[5];
    #pragma unroll
    for (int i = 0; i < 5; i++) acc[i] = (f32x4){0.f, 0.f, 0.f, 0.f};

    const int PI0[4] = {0, 0, 1, 2}, PJ0[4] = {0, 2, 1, 0};
    const int PI1[4] = {0, 1, 1, 2}, PJ1[4] = {1, 0, 2, 1};

    int prb[5], pcb[5];
    #pragma unroll
    for (int i = 0; i < 5; i++) {
        int ci = (wid * 5 + i) * 16 + lq;
        int cis = min(ci, 1088);
        int cr = cis / 33;
        prb[i] = cr;
        pcb[i] = cis - cr * 33 + cofs;
    }

    for (int chunk = 0; chunk < 4; chunk++) {
        __syncthreads();
        for (int u = tid; u < 560; u += 1024) {
            int cp = u & 7, rh = u >> 3;
            int row = rh % 35, half = rh / 35;
            int c0 = chunk * 16 + cp * 2;
            int gr = min(u0r + row, 63);
            const float4* pa = (const float4*)(xe + ((size_t)(b * C_ + c0) * HW + gr) * HW + g0c);
            const float4* pb = (const float4*)(xe + ((size_t)(b * C_ + c0 + 1) * HW + gr) * HW + g0c);
            #pragma unroll
            for (int bb = 0; bb < 5; bb++) {
                int blk = half * 5 + bb;
                float4 va = pa[blk], vb = pb[blk];
                int w0 = (row * UPC2 + blk * 4) * (CSTR2 / 2) + cp;
                xsW[w0     ] = (unsigned)f2bf(va.x) | ((unsigned)f2bf(vb.x) << 16);
                xsW[w0 + 10] = (unsigned)f2bf(va.y) | ((unsigned)f2bf(vb.y) << 16);
                xsW[w0 + 20] = (unsigned)f2bf(va.z) | ((unsigned)f2bf(vb.z) << 16);
                xsW[w0 + 30] = (unsigned)f2bf(va.w) | ((unsigned)f2bf(vb.w) << 16);
            }
        }
        __syncthreads();

        const int aBase = lq * YSTR2 + chunk * 144;
        #pragma unroll
        for (int t4 = 0; t4 < 5; t4++) {
            bf16x8 af;
            int pi, pj;
            if (t4 < 4) {
                int p = 2 * t4 + kgh;
                af = ld_bf8(ysS + aBase + p * 16 + kgl * 8);
                pi = kgh ? PI1[t4] : PI0[t4];
                pj = kgh ? PJ1[t4] : PJ0[t4];
            } else {
                af = ld_bf8(ysS + ((kg < 2) ? (aBase + 8 * 16 + kgl * 8) : (ZOFF_SH + kgl * 8)));
                pi = 2; pj = 2;
            }
            #pragma unroll
            for (int i = 0; i < 5; i++) {
                bf16x8 bf = ld_bf8(xsS + ((prb[i] + pi) * UPC2 + (pcb[i] + pj)) * CSTR2 + kgl * 8);
                acc[i] = __builtin_amdgcn_mfma_f32_16x16x32_bf16(af, bf, acc[i], 0, 0, 0);
            }
        }
    }

    __syncthreads();
    #pragma unroll
    for (int i = 0; i < 5; i++) {
        int ci = (wid * 5 + i) * 16 + lq;
        if (ci < 1089) {
            float xnv = xnL[ci];
            #pragma unroll
            for (int j = 0; j < 4; j++) {
                float v = xnv - 2.0f * acc[i][j];
                unsigned int u = __float_as_uint(v);
                u ^= (unsigned int)((int)u >> 31) | 0x80000000u;
                DlU[(kg * 4 + j) * 1089 + ci] = (u & 0xFFFFF800u) | (unsigned int)ci;
            }
        }
    }
    __syncthreads();

    {
        int q = wid;
        int rq = r0 + (q >> 2), sq = s0 + (q & 3);
        if (rq <= 61 && sq <= 61) {
            int siq = min(max(rq - 15, 0), 32);
            int sjq = min(max(sq - 15, 0), 32);
            int ro = siq - u0r, co = sjq - u0c;
            unsigned int* Dq = DlU + q * 1089;
            const int active = (l < 60);
            const int wi2 = l >> 1, wj0 = (l & 1) * 15;
            const int cbase = (ro + wi2) * 33 + (co + wj0);
            unsigned int myMin = 0xFFFFFFFFu;
            if (active) {
                #pragma unroll
                for (int kk = 0; kk < 15; kk++) myMin = min(myMin, Dq[cbase + kk]);
            }
            int obase = (b * NP + rq * M1 + sq) * NSEL;
            for (int it = 0; it < NSEL; it++) {
                unsigned int lm = myMin;
                #pragma unroll
                for (int off = 32; off >= 1; off >>= 1)
                    lm = min(lm, (unsigned int)__shfl_xor((int)lm, off));
                if (l == 0) {
                    int ci = (int)(lm & 2047u);
                    int cr = ci / 33, cc = ci - (ci / 33) * 33;
                    top_ws[obase + it] = (u0r + cr) * M1 + (u0c + cc);
                }
                if (active && myMin == lm) {
                    int wk = (int)(lm & 2047u) - cbase;
                    Dq[cbase + wk] = 0xFFFFFFFFu;
                    myMin = 0xFFFFFFFFu;
                    #pragma unroll
                    for (int kk = 0; kk < 15; kk++) myMin = min(myMin, Dq[cbase + kk]);
                }
            }
        }
    }
}

// ---------------- K3a: emu from patch-major buffers (dense reads) -----------
__global__ __launch_bounds__(256) void emu_pm_kernel(const float* __restrict__ xpm,
                                                     const float* __restrict__ ypm,
                                                     const float* __restrict__ xnp,
                                                     const float* __restrict__ ynp,
                                                     const int* __restrict__ top_ws,
                                                     float* __restrict__ out_idx,
                                                     float* __restrict__ sv_ws,
                                                     float* __restrict__ dsum_ws) {
    __shared__ float ysE[576];
    __shared__ int topWs[NSEL];
    __shared__ float keyEmu[NSEL];
    __shared__ float selKey[KK];
    __shared__ int   selN[KK];

    const int bid0 = blockIdx.x;
    const int bid = (bid0 & 7) * (B_ * NP / 8) + (bid0 >> 3);  // XCD-affine
    const int b = bid / NP, m = bid - b * NP;
    const int tid = threadIdx.x;
    const float* ybase = ypm + (size_t)(b * NP + m) * 576;

    for (int t = tid; t < 576; t += 256) ysE[t] = ybase[t];
    if (tid < NSEL) topWs[tid] = top_ws[bid * NSEL + tid];
    __syncthreads();

    {
        const int cand = tid >> 4, j = tid & 15;
        const float* xp = xpm + (size_t)(b * NP + topWs[cand]) * 576;
        float acc = 0.f;
        #pragma unroll
        for (int t = 0; t < 36; t++) {
            int e = t * 16 + j;
            acc = fmaf(ysE[e], xp[e], acc);
        }
        float E = acc;
        E = E + __shfl_xor(E, 8, 16);
        E = E + __shfl_xor(E, 4, 16);
        E = E + __shfl_xor(E, 2, 16);
        E = E + __shfl_xor(E, 1, 16);
        if (j == 0) {
            float t0 = -2.0f * E;
            float k1 = t0 + ynp[b * NP + m];
            float k2 = k1 + xnp[b * NP + topWs[cand]];
            keyEmu[cand] = k2 + 1e-5f;
        }
    }
    __syncthreads();

    if (tid == 0) {
        float d[NSEL]; int w[NSEL];
        for (int i = 0; i < NSEL; i++) { d[i] = keyEmu[i]; w[i] = topWs[i]; }
        for (int a = 1; a < NSEL; a++) {
            float dv = d[a]; int wv2 = w[a]; int p = a - 1;
            while (p >= 0 && (d[p] > dv || (d[p] == dv && w[p] > wv2))) {
                d[p + 1] = d[p]; w[p + 1] = w[p]; p--;
            }
            d[p + 1] = dv; w[p + 1] = wv2;
        }
        for (int i = 0; i < KK; i++) { selKey[i] = d[i]; selN[i] = w[i]; }
    }
    __syncthreads();

    if (tid < KK) {
        out_idx[(b * NP + m) * KK + tid] = (float)selN[tid];
        float s10 = selKey[tid] / 10.0f;
        double sv = exp(-(double)s10);
        sv_ws[(b * KK + tid) * NP + m] = (float)sv;
    }

    for (int pair = tid; pair < KK * C_; pair += 256) {
        int k = pair >> 6, c = pair & 63;
        const float* xrow = xpm + (size_t)(b * NP + selN[k]) * 576 + c * 9;
        const float* yrow = ysE + c * 9;
        float a = 0.f;
        #pragma unroll
        for (int p = 0; p < 9; p++) a += fabsf(yrow[p] - xrow[p]);
        dsum_ws[((b * KK + k) * C_ + c) * NP + m] = a;
    }
}

// ---------------- K3b: fallback emu (scattered) ------------------------------
#define XCSTR 584

__global__ __launch_bounds__(256) void emu_fallback_kernel(const float* __restrict__ xe,
                                                           const float* __restrict__ ye,
                                                           const float* __restrict__ xnp,
                                                           const float* __restrict__ ynp,
                                                           const int* __restrict__ top_ws,
                                                           float* __restrict__ out_idx,
                                                           float* __restrict__ sv_ws,
                                                           float* __restrict__ dsum_ws) {
    __shared__ float ysE[576];
    __shared__ int tab[576];
    __shared__ float xc[NSEL * XCSTR];
    __shared__ int topWs[NSEL];
    __shared__ float keyEmu[NSEL];
    __shared__ float selKey[KK];
    __shared__ int   selN[KK];
    __shared__ int   selI[KK];

    const int bid0 = blockIdx.x;
    const int bid = (bid0 & 7) * (B_ * NP / 8) + (bid0 >> 3);
    const int b = bid / NP, m = bid - b * NP;
    const int r = m / M1, s = m - r * M1;
    const int tid = threadIdx.x;
    const float* xb = xe + (size_t)b * C_ * HW * HW;
    const float* yb = ye + (size_t)b * C_ * HW * HW + r * HW + s;

    for (int t = tid; t < 576; t += 256) {
        int c = t / 9, p = t - c * 9;
        tab[t] = c * (HW * HW) + (p / 3) * HW + (p % 3);
    }
    if (tid < NSEL) topWs[tid] = top_ws[bid * NSEL + tid];
    __syncthreads();

    for (int t = tid; t < 576; t += 256) ysE[t] = yb[tab[t]];
    for (int i = tid; i < NSEL * 576; i += 256) {
        int cand = i / 576, e = i - cand * 576;
        int n = topWs[cand];
        int px = n / M1, py = n - px * M1;
        xc[cand * XCSTR + e] = xb[px * HW + py + tab[e]];
    }
    __syncthreads();

    {
        const int cand = tid >> 4, j = tid & 15;
        const float* xcp = xc + cand * XCSTR;
        float acc = 0.f;
        #pragma unroll
        for (int t = 0; t < 36; t++) {
            int e = t * 16 + j;
            acc = fmaf(ysE[e], xcp[e], acc);
        }
        float E = acc;
        E = E + __shfl_xor(E, 8, 16);
        E = E + __shfl_xor(E, 4, 16);
        E = E + __shfl_xor(E, 2, 16);
        E = E + __shfl_xor(E, 1, 16);
        if (j == 0) {
            float t0 = -2.0f * E;
            float k1 = t0 + ynp[b * NP + m];
            float k2 = k1 + xnp[b * NP + topWs[cand]];
            keyEmu[cand] = k2 + 1e-5f;
        }
    }
    __syncthreads();

    if (tid == 0) {
        float d[NSEL]; int w[NSEL]; int ix[NSEL];
        for (int i = 0; i < NSEL; i++) { d[i] = keyEmu[i]; w[i] = topWs[i]; ix[i] = i; }
        for (int a = 1; a < NSEL; a++) {
            float dv = d[a]; int wv2 = w[a]; int iv = ix[a]; int p = a - 1;
            while (p >= 0 && (d[p] > dv || (d[p] == dv && w[p] > wv2))) {
                d[p + 1] = d[p]; w[p + 1] = w[p]; ix[p + 1] = ix[p]; p--;
            }
            d[p + 1] = dv; w[p + 1] = wv2; ix[p + 1] = iv;
        }
        for (int i = 0; i < KK; i++) { selKey[i] = d[i]; selN[i] = w[i]; selI[i] = ix[i]; }
    }
    __syncthreads();

    if (tid < KK) {
        out_idx[(b * NP + m) * KK + tid] = (float)selN[tid];
        float s10 = selKey[tid] / 10.0f;
        double sv = exp(-(double)s10);
        sv_ws[(b * KK + tid) * NP + m] = (float)sv;
    }

    for (int pair = tid; pair < KK * C_; pair += 256) {
        int k = pair >> 6, c = pair & 63;
        const float* xcp = xc + selI[k] * XCSTR + c * 9;
        const float* ycp = ysE + c * 9;
        float a = 0.f;
        #pragma unroll
        for (int p = 0; p < 9; p++) a += fabsf(ycp[p] - xcp[p]);
        dsum_ws[((b * KK + k) * C_ + c) * NP + m] = a;
    }
}

// ---------------- overlap-add image kernels ---------------------------------
__device__ __forceinline__ void oa_range(int y, int& r0, int& r1) {
    r0 = (y >= 5) ? ((y - 4) >> 1) : 0;
    r1 = min(M1 - 1, y >> 1);
}

__global__ __launch_bounds__(256) void score_img_kernel(const float* __restrict__ sv_ws,
                                                        float* __restrict__ out) {
    int idx = blockIdx.x * 256 + threadIdx.x;
    if (idx >= OUT_SCORE_SZ) return;
    int x = idx & 127, y = (idx >> 7) & 127;
    int bk = idx >> 14;
    int r0, r1, s0, s1;
    oa_range(y, r0, r1);
    oa_range(x, s0, s1);
    const float* base = sv_ws + bk * NP;
    float acc = 0.f;
    for (int rr = r0; rr <= r1; rr++)
        for (int ss = s0; ss <= s1; ss++)
            acc += base[rr * M1 + ss];
    out[idx] = acc;
}

__global__ __launch_bounds__(256) void diff_img_sep_kernel(const float* __restrict__ dsum_ws,
                                                           float* __restrict__ out) {
    __shared__ float dpl[NP];
    __shared__ float trow[M1 * HS];
    const int bkc = blockIdx.x;
    const int tid = threadIdx.x;
    const float* src = dsum_ws + (size_t)bkc * NP;

    for (int i = tid; i < NP; i += 256) dpl[i] = src[i];
    __syncthreads();

    for (int u = tid; u < M1 * HS; u += 256) {
        int rr = u >> 7, x = u & 127;
        int s0, s1;
        oa_range(x, s0, s1);
        const float* dr = dpl + rr * M1;
        float a = 0.f;
        for (int ss = s0; ss <= s1; ss++) a += dr[ss];
        trow[rr * HS + x] = a;
    }
    __syncthreads();

    float* dst = out + (size_t)bkc * (HS * HS);
    for (int u = tid; u < HS * HS; u += 256) {
        int y = u >> 7, x = u & 127;
        int r0, r1;
        oa_range(y, r0, r1);
        float a = 0.f;
        for (int rr = r0; rr <= r1; rr++) a += trow[rr * HS + x];
        dst[u] = a;
    }
}

// fused: blocks [0,640) = diff planes; rest = score chunks
__global__ __launch_bounds__(256) void img_fused_kernel(const float* __restrict__ sv_ws,
                                                        const float* __restrict__ dsum_ws,
                                                        float* __restrict__ out) {
    __shared__ float dpl[NP];
    __shared__ float trow[M1 * HS];
    const int tid = threadIdx.x;
    if (blockIdx.x < B_ * KK * C_) {
        const int bkc = blockIdx.x;
        const float* src = dsum_ws + (size_t)bkc * NP;
        for (int i = tid; i < NP; i += 256) dpl[i] = src[i];
        __syncthreads();
        for (int u = tid; u < M1 * HS; u += 256) {
            int rr = u >> 7, x = u & 127;
            int s0, s1;
            oa_range(x, s0, s1);
            const float* dr = dpl + rr * M1;
            float a = 0.f;
            for (int ss = s0; ss <= s1; ss++) a += dr[ss];
            trow[rr * HS + x] = a;
        }
        __syncthreads();
        float* dst = out + OUT_DIFF_OFF + (size_t)bkc * (HS * HS);
        for (int u = tid; u < HS * HS; u += 256) {
            int y = u >> 7, x = u & 127;
            int r0, r1;
            oa_range(y, r0, r1);
            float a = 0.f;
            for (int rr = r0; rr <= r1; rr++) a += trow[rr * HS + x];
            dst[u] = a;
        }
    } else {
        int idx = (blockIdx.x - B_ * KK * C_) * 256 + tid;
        if (idx >= OUT_SCORE_SZ) return;
        int x = idx & 127, y = (idx >> 7) & 127;
        int bk = idx >> 14;
        int r0, r1, s0, s1;
        oa_range(y, r0, r1);
        oa_range(x, s0, s1);
        const float* base = sv_ws + bk * NP;
        float acc = 0.f;
        for (int rr = r0; rr <= r1; rr++)
            for (int ss = s0; ss <= s1; ss++)
                acc += base[rr * M1 + ss];
        out[idx] = acc;
    }
}

extern "C" void kernel_launch(void* const* d_in, const int* in_sizes, int n_in,
                              void* d_out, int out_size, void* d_ws, size_t ws_size,
                              hipStream_t stream) {
    const float* xe = (const float*)d_in[0];
    const float* ye = (const float*)d_in[1];
    float* out = (float*)d_out;
    float* ws = (float*)d_ws;

    float* xnp = ws + WS_XNP;
    float* ynp = ws + WS_YNP;
    int*   topw = (int*)(ws + WS_TOP);
    float* sv_ws = ws + WS_SV;
    float* dsum_ws = ws + WS_DSUM;
    float* xpm = ws + WS_XPM;
    float* ypm = ws + WS_YPM;
    unsigned int* ypbfW = (unsigned int*)(ws + WS_YPBF);
    unsigned int* xebfW = (unsigned int*)(ws + WS_XEBF);

    const bool pm_ok = (ws_size >= WS_NEED_BYTES);
    const int normBlocks = (2 * B_ * NP * 8 + 255) / 256;

    if (pm_ok) {
        prep_fused_kernel<<<B_ * HW + 2 * B_ * M1, 256, 0, stream>>>(xe, ye, xebfW, xpm, ypm, ypbfW);
        norm_np_pm_kernel<<<normBlocks, 256, 0, stream>>>(xpm, ypm, xnp, ynp);
        gemm32_kernel<<<B_ * 128, 1024, 0, stream>>>((const unsigned short*)ypbfW,
                                                     (const unsigned short*)xebfW, xnp, topw);
        emu_pm_kernel<<<B_ * NP, 256, 0, stream>>>(xpm, ypm, xnp, ynp, topw,
                                                   out + OUT_IDX_OFF, sv_ws, dsum_ws);
        img_fused_kernel<<<B_ * KK * C_ + OUT_SCORE_SZ / 256, 256, 0, stream>>>(sv_ws, dsum_ws, out);
    } else {
        norm_np_kernel<<<normBlocks, 256, 0, stream>>>(xe, ye, xnp, ynp);
        gemm_select_fb<<<2 * 256, 1024, 0, stream>>>(xe, ye, xnp, topw);
        emu_fallback_kernel<<<B_ * NP, 256, 0, stream>>>(xe, ye, xnp, ynp, topw,
                                                         out + OUT_IDX_OFF, sv_ws, dsum_ws);
        score_img_kernel<<<OUT_SCORE_SZ / 256, 256, 0, stream>>>(sv_ws, out);
        diff_img_sep_kernel<<<B_ * KK * C_, 256, 0, stream>>>(dsum_ws, out + OUT_DIFF_OFF);
    }
}

// Round 18
// 128.695 us; speedup vs baseline: 1.3937x; 1.1538x over previous
//
#include <hip/hip_runtime.h>
#include <float.h>
#include <math.h>

#define B_ 2
#define C_ 64
#define HW 64
#define M1 62
#define NP (M1*M1)      // 3844
#define WIN 30
#define KK 5
#define NSEL 16
#define HS 128

#define OUT_SCORE_SZ (B_*KK*HS*HS)       // 163840
#define OUT_IDX_OFF  (OUT_SCORE_SZ)
#define OUT_IDX_SZ   (B_*NP*KK)          // 38440
#define OUT_DIFF_OFF (OUT_IDX_OFF+OUT_IDX_SZ)
#define OUT_DIFF_SZ  (B_*KK*C_*HS*HS)    // 10485760

// ws layout in floats
#define WS_XNP 0
#define WS_YNP 8192
#define WS_TOP 16384                      // ints: B_*NP*16 = 123008
#define WS_SV  (16384+123008)             // 139392
#define WS_DSUM (139392+40960)            // 180352
#define WS_XPM  (180352+2460160)          // 2640512
#define XPM_F   (B_*NP*576)               // 4428288 floats
#define WS_YPM  (WS_XPM + XPM_F)          // 7068800
#define WS_YPBF (WS_YPM + XPM_F)          // 11497088 (ushorts: B_*NP*576)
#define WS_XEBF (WS_YPBF + XPM_F/2)       // 13711232 (ushorts: B_*64*64*64)
#define WS_END  (WS_XEBF + 262144)        // 13973376
#define WS_NEED_BYTES ((size_t)WS_END * 4)   // ~55.9 MB

typedef __attribute__((ext_vector_type(8))) short bf16x8;
typedef __attribute__((ext_vector_type(4))) short bf16x4;
typedef __attribute__((ext_vector_type(4))) short s16x4;
typedef __attribute__((ext_vector_type(4))) float f32x4;
typedef __attribute__((ext_vector_type(16))) float f32x16;

__device__ __forceinline__ unsigned short f2bf(float f) {
    union { float f; unsigned int u; } v; v.f = f;
    unsigned int r = (v.u + 0x7FFFu + ((v.u >> 16) & 1u)) >> 16;
    return (unsigned short)r;
}

__device__ __forceinline__ bf16x8 ld_bf8(const short* p) {
    bf16x4 lo = *(const bf16x4*)p;
    bf16x4 hi = *(const bf16x4*)(p + 4);
    bf16x8 r;
    r[0] = lo[0]; r[1] = lo[1]; r[2] = lo[2]; r[3] = lo[3];
    r[4] = hi[0]; r[5] = hi[1]; r[6] = hi[2]; r[7] = hi[3];
    return r;
}

// ---------------- K0: fused prep (xebf pixel-major bf16 + im2patch), 512t ---
__global__ __launch_bounds__(512) void prep_fused_kernel(const float* __restrict__ xe,
                                                         const float* __restrict__ ye,
                                                         unsigned int* __restrict__ xebfW,
                                                         float* __restrict__ xpm,
                                                         float* __restrict__ ypm,
                                                         unsigned int* __restrict__ ypbfW) {
    __shared__ __align__(16) unsigned char sm[64 * 192 * 4 + 1152 * 4];
    const int tid = threadIdx.x;
    const int bid = blockIdx.x;

    if (bid < B_ * HW) {
        float* tile = (float*)sm;   // 64*65 floats
        int b = bid >> 6, h = bid & 63;
        for (int i = tid; i < 4096; i += 512) {
            int c = i >> 6, w = i & 63;
            tile[c * 65 + w] = xe[(((size_t)b * C_ + c) * HW + h) * HW + w];
        }
        __syncthreads();
        for (int j = tid; j < 2048; j += 512) {
            int w = j >> 5, cp = j & 31;
            unsigned int u = (unsigned int)f2bf(tile[(2 * cp) * 65 + w])
                           | ((unsigned int)f2bf(tile[(2 * cp + 1) * 65 + w]) << 16);
            xebfW[(((size_t)b * HW + h) * HW + w) * 32 + cp] = u;
        }
    } else {
        int bid2 = bid - B_ * HW;
        float* rows = (float*)sm;                     // 64*192
        int* tabL = (int*)(sm + 64 * 192 * 4);
        int* tabP = tabL + 576;
        const int srcI = bid2 / (B_ * M1);
        const int rem = bid2 - srcI * (B_ * M1);
        const int b = rem / M1, r = rem - b * M1;
        const float* src = (srcI ? ye : xe) + (size_t)b * C_ * HW * HW;
        float* dst = (srcI ? ypm : xpm) + (size_t)(b * NP + r * M1) * 576;

        for (int t = tid; t < 576; t += 512) {
            int c = t / 9, p = t - c * 9;
            tabL[t] = c * 192 + (p / 3) * 64 + (p % 3);
            int cj = (t / 144) * 16 + (t & 15), pj = (t % 144) >> 4;
            tabP[t] = cj * 192 + (pj / 3) * 64 + (pj % 3);
        }
        for (int i = tid; i < 64 * 192; i += 512) {
            rows[i] = src[(i / 192) * (HW * HW) + r * HW + (i % 192)];
        }
        __syncthreads();

        // two s-values per iteration: half-block each (62 = 31 pairs)
        const int sh = tid >> 8;           // 0 or 1
        const int tl = tid & 255;
        for (int s2 = 0; s2 < M1; s2 += 2) {
            int s = s2 + sh;
            float* d = dst + s * 576;
            for (int e = tl; e < 576; e += 256) d[e] = rows[tabL[e] + s];
            if (srcI) {
                unsigned int* yb = ypbfW + (size_t)(b * NP + r * M1 + s) * 288;
                for (int j2 = tl; j2 < 288; j2 += 256) {
                    unsigned int u = (unsigned int)f2bf(rows[tabP[2 * j2] + s])
                                   | ((unsigned int)f2bf(rows[tabP[2 * j2 + 1] + s]) << 16);
                    yb[j2] = u;
                }
            }
        }
    }
}

// ---------------- K1a: numpy-pairwise norms, dense reads from pm ------------
__global__ __launch_bounds__(256) void norm_np_pm_kernel(const float* __restrict__ xpm,
                                                         const float* __restrict__ ypm,
                                                         float* __restrict__ xnp,
                                                         float* __restrict__ ynp) {
    int gid = blockIdx.x * 256 + threadIdx.x;
    if (gid >= 2 * B_ * NP * 8) return;
    int which = gid / (B_ * NP * 8);
    int rem = gid - which * (B_ * NP * 8);
    int patch = rem >> 3, leaf = rem & 7;
    const float* src = (which ? ypm : xpm) + (size_t)patch * 576 + leaf * 72;

    float a8[8];
    #pragma unroll
    for (int i = 0; i < 8; i++) { float v = src[i]; a8[i] = v * v; }
    for (int i0 = 8; i0 < 72; i0 += 8) {
        #pragma unroll
        for (int i = 0; i < 8; i++) { float v = src[i0 + i]; a8[i] += v * v; }
    }
    float t = ((a8[0] + a8[1]) + (a8[2] + a8[3])) + ((a8[4] + a8[5]) + (a8[6] + a8[7]));
    t = t + __shfl_xor(t, 1, 8);
    t = t + __shfl_xor(t, 2, 8);
    t = t + __shfl_xor(t, 4, 8);
    if (leaf == 0) (which ? ynp : xnp)[patch] = t;
}

// ---------------- K1b: fallback norms (scattered) ---------------------------
__global__ __launch_bounds__(256) void norm_np_kernel(const float* __restrict__ xe,
                                                      const float* __restrict__ ye,
                                                      float* __restrict__ xnp,
                                                      float* __restrict__ ynp) {
    __shared__ int tab[576];
    for (int t = threadIdx.x; t < 576; t += 256) {
        int c = t / 9, p = t - c * 9;
        tab[t] = c * (HW * HW) + (p / 3) * HW + (p % 3);
    }
    __syncthreads();

    int gid = blockIdx.x * 256 + threadIdx.x;
    if (gid >= 2 * B_ * NP * 8) return;
    int which = gid / (B_ * NP * 8);
    int rem = gid - which * (B_ * NP * 8);
    int patch = rem >> 3, leaf = rem & 7;
    int b = patch / NP, m = patch - b * NP;
    int r = m / M1, s = m - r * M1;
    const float* src = (which ? ye : xe) + (size_t)b * C_ * HW * HW + r * HW + s;

    int base = leaf * 72;
    float a8[8];
    #pragma unroll
    for (int i = 0; i < 8; i++) { float v = src[tab[base + i]]; a8[i] = v * v; }
    for (int i0 = 8; i0 < 72; i0 += 8) {
        #pragma unroll
        for (int i = 0; i < 8; i++) { float v = src[tab[base + i0 + i]]; a8[i] += v * v; }
    }
    float t = ((a8[0] + a8[1]) + (a8[2] + a8[3])) + ((a8[4] + a8[5]) + (a8[6] + a8[7]));
    t = t + __shfl_xor(t, 1, 8);
    t = t + __shfl_xor(t, 2, 8);
    t = t + __shfl_xor(t, 4, 8);
    if (leaf == 0) (which ? ynp : xnp)[patch] = t;
}

// ---------------- K2: 32x32 MFMA prescreen -----------------------------------
#define UROW 39
#define UCOL 35
#define PSTR 24
#define QSTR 584
#define G_YOFF (UROW*UCOL*PSTR*2)
#define G_XNOFF (G_YOFF + 32*QSTR*2)
#define G_SM (G_XNOFF + 1280*4)

__global__ __launch_bounds__(1024, 4) void gemm32_kernel(const unsigned short* __restrict__ ypbf,
                                                         const unsigned short* __restrict__ xebf,
                                                         const float* __restrict__ xnp,
                                                         int* __restrict__ top_ws) {
    __shared__ __align__(16) unsigned char smem[G_SM];
    short* xs = (short*)smem;
    short* ysS = (short*)(smem + G_YOFF);
    float* xnL = (float*)(smem + G_XNOFF);
    unsigned int* DlU = (unsigned int*)smem;

    const int bid = blockIdx.x;
    const int b = bid >> 7;
    const int t = bid & 127;
    const int r0 = (t >> 4) * 8;
    const int s0 = (t & 15) * 4;
    const int u0r = min(max(r0 - 15, 0), 32);
    const int u0c = min(max(s0 - 15, 0), 32);
    const int tid = threadIdx.x;
    const int l = tid & 63;
    const int w = tid >> 6;
    const int lq = l & 31;
    const int kh = l >> 5;

    for (int u = tid; u < 32 * 144; u += 1024) {
        int q = u / 144, j4 = u - q * 144;
        int rq = min(r0 + (q >> 2), 61), sq = min(s0 + (q & 3), 61);
        s16x4 v = *(const s16x4*)(ypbf + (size_t)(b * NP + rq * M1 + sq) * 576 + j4 * 4);
        *(s16x4*)(ysS + q * QSTR + j4 * 4) = v;
    }
    for (int i = tid; i < 1221; i += 1024) {
        int cr = i / 33, cc = i - cr * 33;
        int nr = min(u0r + cr, 61), nc = min(u0c + cc, 61);
        xnL[i] = xnp[b * NP + nr * M1 + nc];
    }

    int crA[3], ccA[3];
    #pragma unroll
    for (int t3 = 0; t3 < 3; t3++) {
        int tile = t3 * 16 + w;
        int ci = min(tile * 32 + lq, 1220);
        int cr = ci / 33;
        crA[t3] = cr;
        ccA[t3] = ci - cr * 33;
    }
    const bool v2 = (w < 7);

    f32x16 acc0 = {}, acc1 = {}, acc2 = {};

    for (int chunk = 0; chunk < 4; chunk++) {
        __syncthreads();
        for (int u = tid; u < UROW * UCOL; u += 1024) {
            int rr = u / UCOL, c2 = u - rr * UCOL;
            int gr = min(u0r + rr, 63), gc = min(u0c + c2, 63);
            const unsigned short* sp = xebf + ((((size_t)b * HW + gr) * HW + gc) << 6) + chunk * 16;
            int4 v0 = *(const int4*)sp;
            int4 v1 = *(const int4*)(sp + 8);
            *(int4*)(xs + u * PSTR) = v0;
            *(int4*)(xs + u * PSTR + 8) = v1;
        }
        __syncthreads();

        #pragma unroll
        for (int p = 0; p < 9; p++) {
            const int pi = p / 3, pj = p % 3;
            bf16x8 af = *(const bf16x8*)(ysS + lq * QSTR + chunk * 144 + p * 16 + kh * 8);
            {
                const short* bp = xs + ((crA[0] + pi) * UCOL + (ccA[0] + pj)) * PSTR + kh * 8;
                acc0 = __builtin_amdgcn_mfma_f32_32x32x16_bf16(af, *(const bf16x8*)bp, acc0, 0, 0, 0);
            }
            {
                const short* bp = xs + ((crA[1] + pi) * UCOL + (ccA[1] + pj)) * PSTR + kh * 8;
                acc1 = __builtin_amdgcn_mfma_f32_32x32x16_bf16(af, *(const bf16x8*)bp, acc1, 0, 0, 0);
            }
            if (v2) {
                const short* bp = xs + ((crA[2] + pi) * UCOL + (ccA[2] + pj)) * PSTR + kh * 8;
                acc2 = __builtin_amdgcn_mfma_f32_32x32x16_bf16(af, *(const bf16x8*)bp, acc2, 0, 0, 0);
            }
        }
    }

    for (int ph = 0; ph < 2; ph++) {
        __syncthreads();
        #pragma unroll
        for (int t3 = 0; t3 < 3; t3++) {
            if (t3 == 2 && !v2) continue;
            int ci = (t3 * 16 + w) * 32 + lq;
            if (ci <= 1220) {
                float xnv = xnL[ci];
                #pragma unroll
                for (int j = 0; j < 8; j++) {
                    int jj = ph * 8 + j;
                    float av = (t3 == 0) ? acc0[jj] : (t3 == 1 ? acc1[jj] : acc2[jj]);
                    int row = (jj & 3) + 8 * (jj >> 2) + 4 * kh;
                    float v = xnv - 2.0f * av;
                    unsigned int u = __float_as_uint(v);
                    u ^= (unsigned int)((int)u >> 31) | 0x80000000u;
                    DlU[(row - ph * 16) * 1280 + ci] = (u & 0xFFFFF800u) | (unsigned int)ci;
                }
            }
        }
        __syncthreads();
        {
            int q = ph * 16 + w;
            int rq = r0 + (q >> 2), sq = s0 + (q & 3);
            if (rq <= 61 && sq <= 61) {
                int siq = min(max(rq - 15, 0), 32);
                int sjq = min(max(sq - 15, 0), 32);
                int ro = siq - u0r, co = sjq - u0c;
                unsigned int* Dq = DlU + w * 1280;
                const int active = (l < 60);
                const int wi2 = l >> 1, wj0 = (l & 1) * 15;
                const int cbase = (ro + wi2) * 33 + (co + wj0);
                unsigned int myMin = 0xFFFFFFFFu;
                if (active) {
                    #pragma unroll
                    for (int kk = 0; kk < 15; kk++) myMin = min(myMin, Dq[cbase + kk]);
                }
                int obase = (b * NP + rq * M1 + sq) * NSEL;
                for (int it = 0; it < NSEL; it++) {
                    unsigned int lm = myMin;
                    #pragma unroll
                    for (int off = 32; off >= 1; off >>= 1)
                        lm = min(lm, (unsigned int)__shfl_xor((int)lm, off));
                    if (l == 0) {
                        int ci = (int)(lm & 2047u);
                        int cr = ci / 33, cc = ci - (ci / 33) * 33;
                        top_ws[obase + it] = (u0r + cr) * M1 + (u0c + cc);
                    }
                    if (active && myMin == lm) {
                        int wk = (int)(lm & 2047u) - cbase;
                        Dq[cbase + wk] = 0xFFFFFFFFu;
                        myMin = 0xFFFFFFFFu;
                        #pragma unroll
                        for (int kk = 0; kk < 15; kk++) myMin = min(myMin, Dq[cbase + kk]);
                    }
                }
            }
        }
    }
}

// ---------------- K2-fb: old 16x16 prescreen (scattered staging) ------------
#define UPC2 40
#define CSTR2 20
#define YSTR2 580
#define ZOFF_SH (16*YSTR2)
#define YS2_OFF 56000
#define XN2_OFF (YS2_OFF + (ZOFF_SH+16)*2)
#define SM2_BYTES (XN2_OFF + 1089*4)

__global__ __launch_bounds__(1024, 4) void gemm_select_fb(const float* __restrict__ xe,
                                                          const float* __restrict__ ye,
                                                          const float* __restrict__ xnp,
                                                          int* __restrict__ top_ws) {
    __shared__ __align__(16) unsigned char smem[SM2_BYTES];
    short* xsS = (short*)smem;
    unsigned int* xsW = (unsigned int*)smem;
    short* ysS = (short*)(smem + YS2_OFF);
    float* xnL = (float*)(smem + XN2_OFF);
    unsigned int* DlU = (unsigned int*)smem;

    const int bid = blockIdx.x;
    const int b  = bid >> 8;
    const int t  = bid & 255;
    const int r0 = (t >> 4) * 4;
    const int s0 = (t & 15) * 4;
    const int u0r = min(max(r0 - 15, 0), 32);
    const int u0c = min(max(s0 - 15, 0), 32);
    const int g0c = min(u0c & ~3, 24);
    const int cofs = u0c - g0c;
    const int tid = threadIdx.x;
    const int l   = tid & 63;
    const int wid = tid >> 6;
    const int lq  = l & 15;
    const int kg  = l >> 4;
    const int kgh = kg >> 1, kgl = kg & 1;

    for (int u = tid; u < 16 * 576; u += 1024) {
        int q = u / 576, e = u - q * 576;
        int rq = min(r0 + (q >> 2), 61), sq = min(s0 + (q & 3), 61);
        int c = e / 9, p = e - c * 9;
        float v = ye[((b * C_ + c) * HW + rq + p / 3) * HW + sq + p % 3];
        ysS[q * YSTR2 + (c >> 4) * 144 + p * 16 + (c & 15)] = (short)f2bf(v);
    }
    if (tid < 16) ysS[ZOFF_SH + tid] = 0;
    for (int i = tid; i < 1089; i += 1024) {
        int cr = i / 33, cc = i - cr * 33;
        int nr = min(u0r + cr, 61), nc = min(u0c + cc, 61);
        xnL[i] = xnp[b * NP + nr * M1 + nc];
    }

    f32x4 acc[5];
    #pragma unroll
    for (int i = 0; i < 5; i++) acc[i] = (f32x4){0.f, 0.f, 0.f, 0.f};

    const int PI0[4] = {0, 0, 1, 2}, PJ0[4] = {0, 2, 1, 0};
    const int PI1[4] = {0, 1, 1, 2}, PJ1[4] = {1, 0, 2, 1};

    int prb[5], pcb[5];
    #pragma unroll
    for (int i = 0; i < 5; i++) {
        int ci = (wid * 5 + i) * 16 + lq;
        int cis = min(ci, 1088);
        int cr = cis / 33;
        prb[i] = cr;
        pcb[i] = cis - cr * 33 + cofs;
    }

    for (int chunk = 0; chunk < 4; chunk++) {
        __syncthreads();
        for (int u = tid; u < 560; u += 1024) {
            int cp = u & 7, rh = u >> 3;
            int row = rh % 35, half = rh / 35;
            int c0 = chunk * 16 + cp * 2;
            int gr = min(u0r + row, 63);
            const float4* pa = (const float4*)(xe + ((size_t)(b * C_ + c0) * HW + gr) * HW + g0c);
            const float4* pb = (const float4*)(xe + ((size_t)(b * C_ + c0 + 1) * HW + gr) * HW + g0c);
            #pragma unroll
            for (int bb = 0; bb < 5; bb++) {
                int blk = half * 5 + bb;
                float4 va = pa[blk], vb = pb[blk];
                int w0 = (row * UPC2 + blk * 4) * (CSTR2 / 2) + cp;
                xsW[w0     ] = (unsigned)f2bf(va.x) | ((unsigned)f2bf(vb.x) << 16);
                xsW[w0 + 10] = (unsigned)f2bf(va.y) | ((unsigned)f2bf(vb.y) << 16);
                xsW[w0 + 20] = (unsigned)f2bf(va.z) | ((unsigned)f2bf(vb.z) << 16);
                xsW[w0 + 30] = (unsigned)f2bf(va.w) | ((unsigned)f2bf(vb.w) << 16);
            }
        }
        __syncthreads();

        const int aBase = lq * YSTR2 + chunk * 144;
        #pragma unroll
        for (int t4 = 0; t4 < 5; t4++) {
            bf16x8 af;
            int pi, pj;
            if (t4 < 4) {
                int p = 2 * t4 + kgh;
                af = ld_bf8(ysS + aBase + p * 16 + kgl * 8);
                pi = kgh ? PI1[t4] : PI0[t4];
                pj = kgh ? PJ1[t4] : PJ0[t4];
            } else {
                af = ld_bf8(ysS + ((kg < 2) ? (aBase + 8 * 16 + kgl * 8) : (ZOFF_SH + kgl * 8)));
                pi = 2; pj = 2;
            }
            #pragma unroll
            for (int i = 0; i < 5; i++) {
                bf16x8 bf = ld_bf8(xsS + ((prb[i] + pi) * UPC2 + (pcb[i] + pj)) * CSTR2 + kgl * 8);
                acc[i] = __builtin_amdgcn_mfma_f32_16x16x32_bf16(af, bf, acc[i], 0, 0, 0);
            }
        }
    }

    __syncthreads();
    #pragma unroll
    for (int i = 0; i < 5; i++) {
        int ci = (wid * 5 + i) * 16 + lq;
        if (ci < 1089) {
            float xnv = xnL[ci];
            #pragma unroll
            for (int j = 0; j < 4; j++) {
                float v = xnv - 2.0f * acc[i][j];
                unsigned int u = __float_as_uint(v);
                u ^= (unsigned int)((int)u >> 31) | 0x80000000u;
                DlU[(kg * 4 + j) * 1089 + ci] = (u & 0xFFFFF800u) | (unsigned int)ci;
            }
        }
    }
    __syncthreads();

    {
        int q = wid;
        int rq = r0 + (q >> 2), sq = s0 + (q & 3);
        if (rq <= 61 && sq <= 61) {
            int siq = min(max(rq - 15, 0), 32);
            int sjq = min(max(sq - 15, 0), 32);
            int ro = siq - u0r, co = sjq - u0c;
            unsigned int* Dq = DlU + q * 1089;
            const int active = (l < 60);
            const int wi2 = l >> 1, wj0 = (l & 1) * 15;
            const int cbase = (ro + wi2) * 33 + (co + wj0);
            unsigned int myMin = 0xFFFFFFFFu;
            if (active) {
                #pragma unroll
                for (int kk = 0; kk < 15; kk++) myMin = min(myMin, Dq[cbase + kk]);
            }
            int obase = (b * NP + rq * M1 + sq) * NSEL;
            for (int it = 0; it < NSEL; it++) {
                unsigned int lm = myMin;
                #pragma unroll
                for (int off = 32; off >= 1; off >>= 1)
                    lm = min(lm, (unsigned int)__shfl_xor((int)lm, off));
                if (l == 0) {
                    int ci = (int)(lm & 2047u);
                    int cr = ci / 33, cc = ci - (ci / 33) * 33;
                    top_ws[obase + it] = (u0r + cr) * M1 + (u0c + cc);
                }
                if (active && myMin == lm) {
                    int wk = (int)(lm & 2047u) - cbase;
                    Dq[cbase + wk] = 0xFFFFFFFFu;
                    myMin = 0xFFFFFFFFu;
                    #pragma unroll
                    for (int kk = 0; kk < 15; kk++) myMin = min(myMin, Dq[cbase + kk]);
                }
            }
        }
    }
}

// ---------------- K3a: emu from patch-major buffers (dense reads) -----------
__global__ __launch_bounds__(256) void emu_pm_kernel(const float* __restrict__ xpm,
                                                     const float* __restrict__ ypm,
                                                     const float* __restrict__ xnp,
                                                     const float* __restrict__ ynp,
                                                     const int* __restrict__ top_ws,
                                                     float* __restrict__ out_idx,
                                                     float* __restrict__ sv_ws,
                                                     float* __restrict__ dsum_ws) {
    __shared__ float ysE[576];
    __shared__ int topWs[NSEL];
    __shared__ float keyEmu[NSEL];
    __shared__ float selKey[KK];
    __shared__ int   selN[KK];

    const int bid0 = blockIdx.x;
    const int bid = (bid0 & 7) * (B_ * NP / 8) + (bid0 >> 3);  // XCD-affine
    const int b = bid / NP, m = bid - b * NP;
    const int tid = threadIdx.x;
    const float* ybase = ypm + (size_t)(b * NP + m) * 576;

    for (int t = tid; t < 576; t += 256) ysE[t] = ybase[t];
    if (tid < NSEL) topWs[tid] = top_ws[bid * NSEL + tid];
    __syncthreads();

    {
        const int cand = tid >> 4, j = tid & 15;
        const float* xp = xpm + (size_t)(b * NP + topWs[cand]) * 576;
        float acc = 0.f;
        #pragma unroll
        for (int t = 0; t < 36; t++) {
            int e = t * 16 + j;
            acc = fmaf(ysE[e], xp[e], acc);
        }
        float E = acc;
        E = E + __shfl_xor(E, 8, 16);
        E = E + __shfl_xor(E, 4, 16);
        E = E + __shfl_xor(E, 2, 16);
        E = E + __shfl_xor(E, 1, 16);
        if (j == 0) {
            float t0 = -2.0f * E;
            float k1 = t0 + ynp[b * NP + m];
            float k2 = k1 + xnp[b * NP + topWs[cand]];
            keyEmu[cand] = k2 + 1e-5f;
        }
    }
    __syncthreads();

    if (tid == 0) {
        float d[NSEL]; int w[NSEL];
        for (int i = 0; i < NSEL; i++) { d[i] = keyEmu[i]; w[i] = topWs[i]; }
        for (int a = 1; a < NSEL; a++) {
            float dv = d[a]; int wv2 = w[a]; int p = a - 1;
            while (p >= 0 && (d[p] > dv || (d[p] == dv && w[p] > wv2))) {
                d[p + 1] = d[p]; w[p + 1] = w[p]; p--;
            }
            d[p + 1] = dv; w[p + 1] = wv2;
        }
        for (int i = 0; i < KK; i++) { selKey[i] = d[i]; selN[i] = w[i]; }
    }
    __syncthreads();

    if (tid < KK) {
        out_idx[(b * NP + m) * KK + tid] = (float)selN[tid];
        float s10 = selKey[tid] / 10.0f;
        double sv = exp(-(double)s10);
        sv_ws[(b * KK + tid) * NP + m] = (float)sv;
    }

    for (int pair = tid; pair < KK * C_; pair += 256) {
        int k = pair >> 6, c = pair & 63;
        const float* xrow = xpm + (size_t)(b * NP + selN[k]) * 576 + c * 9;
        const float* yrow = ysE + c * 9;
        float a = 0.f;
        #pragma unroll
        for (int p = 0; p < 9; p++) a += fabsf(yrow[p] - xrow[p]);
        dsum_ws[((b * KK + k) * C_ + c) * NP + m] = a;
    }
}

// ---------------- K3b: fallback emu (scattered) ------------------------------
#define XCSTR 584

__global__ __launch_bounds__(256) void emu_fallback_kernel(const float* __restrict__ xe,
                                                           const float* __restrict__ ye,
                                                           const float* __restrict__ xnp,
                                                           const float* __restrict__ ynp,
                                                           const int* __restrict__ top_ws,
                                                           float* __restrict__ out_idx,
                                                           float* __restrict__ sv_ws,
                                                           float* __restrict__ dsum_ws) {
    __shared__ float ysE[576];
    __shared__ int tab[576];
    __shared__ float xc[NSEL * XCSTR];
    __shared__ int topWs[NSEL];
    __shared__ float keyEmu[NSEL];
    __shared__ float selKey[KK];
    __shared__ int   selN[KK];
    __shared__ int   selI[KK];

    const int bid0 = blockIdx.x;
    const int bid = (bid0 & 7) * (B_ * NP / 8) + (bid0 >> 3);
    const int b = bid / NP, m = bid - b * NP;
    const int r = m / M1, s = m - r * M1;
    const int tid = threadIdx.x;
    const float* xb = xe + (size_t)b * C_ * HW * HW;
    const float* yb = ye + (size_t)b * C_ * HW * HW + r * HW + s;

    for (int t = tid; t < 576; t += 256) {
        int c = t / 9, p = t - c * 9;
        tab[t] = c * (HW * HW) + (p / 3) * HW + (p % 3);
    }
    if (tid < NSEL) topWs[tid] = top_ws[bid * NSEL + tid];
    __syncthreads();

    for (int t = tid; t < 576; t += 256) ysE[t] = yb[tab[t]];
    for (int i = tid; i < NSEL * 576; i += 256) {
        int cand = i / 576, e = i - cand * 576;
        int n = topWs[cand];
        int px = n / M1, py = n - px * M1;
        xc[cand * XCSTR + e] = xb[px * HW + py + tab[e]];
    }
    __syncthreads();

    {
        const int cand = tid >> 4, j = tid & 15;
        const float* xcp = xc + cand * XCSTR;
        float acc = 0.f;
        #pragma unroll
        for (int t = 0; t < 36; t++) {
            int e = t * 16 + j;
            acc = fmaf(ysE[e], xcp[e], acc);
        }
        float E = acc;
        E = E + __shfl_xor(E, 8, 16);
        E = E + __shfl_xor(E, 4, 16);
        E = E + __shfl_xor(E, 2, 16);
        E = E + __shfl_xor(E, 1, 16);
        if (j == 0) {
            float t0 = -2.0f * E;
            float k1 = t0 + ynp[b * NP + m];
            float k2 = k1 + xnp[b * NP + topWs[cand]];
            keyEmu[cand] = k2 + 1e-5f;
        }
    }
    __syncthreads();

    if (tid == 0) {
        float d[NSEL]; int w[NSEL]; int ix[NSEL];
        for (int i = 0; i < NSEL; i++) { d[i] = keyEmu[i]; w[i] = topWs[i]; ix[i] = i; }
        for (int a = 1; a < NSEL; a++) {
            float dv = d[a]; int wv2 = w[a]; int iv = ix[a]; int p = a - 1;
            while (p >= 0 && (d[p] > dv || (d[p] == dv && w[p] > wv2))) {
                d[p + 1] = d[p]; w[p + 1] = w[p]; ix[p + 1] = ix[p]; p--;
            }
            d[p + 1] = dv; w[p + 1] = wv2; ix[p + 1] = iv;
        }
        for (int i = 0; i < KK; i++) { selKey[i] = d[i]; selN[i] = w[i]; selI[i] = ix[i]; }
    }
    __syncthreads();

    if (tid < KK) {
        out_idx[(b * NP + m) * KK + tid] = (float)selN[tid];
        float s10 = selKey[tid] / 10.0f;
        double sv = exp(-(double)s10);
        sv_ws[(b * KK + tid) * NP + m] = (float)sv;
    }

    for (int pair = tid; pair < KK * C_; pair += 256) {
        int k = pair >> 6, c = pair & 63;
        const float* xcp = xc + selI[k] * XCSTR + c * 9;
        const float* ycp = ysE + c * 9;
        float a = 0.f;
        #pragma unroll
        for (int p = 0; p < 9; p++) a += fabsf(ycp[p] - xcp[p]);
        dsum_ws[((b * KK + k) * C_ + c) * NP + m] = a;
    }
}

// ---------------- overlap-add image kernels ---------------------------------
__device__ __forceinline__ void oa_range(int y, int& r0, int& r1) {
    r0 = (y >= 5) ? ((y - 4) >> 1) : 0;
    r1 = min(M1 - 1, y >> 1);
}

__global__ __launch_bounds__(256) void score_img_kernel(const float* __restrict__ sv_ws,
                                                        float* __restrict__ out) {
    int idx = blockIdx.x * 256 + threadIdx.x;
    if (idx >= OUT_SCORE_SZ) return;
    int x = idx & 127, y = (idx >> 7) & 127;
    int bk = idx >> 14;
    int r0, r1, s0, s1;
    oa_range(y, r0, r1);
    oa_range(x, s0, s1);
    const float* base = sv_ws + bk * NP;
    float acc = 0.f;
    for (int rr = r0; rr <= r1; rr++)
        for (int ss = s0; ss <= s1; ss++)
            acc += base[rr * M1 + ss];
    out[idx] = acc;
}

__global__ __launch_bounds__(256) void diff_img_sep_kernel(const float* __restrict__ dsum_ws,
                                                           float* __restrict__ out) {
    __shared__ float dpl[NP];
    __shared__ float trow[M1 * HS];
    const int bkc = blockIdx.x;
    const int tid = threadIdx.x;
    const float* src = dsum_ws + (size_t)bkc * NP;

    for (int i = tid; i < NP; i += 256) dpl[i] = src[i];
    __syncthreads();

    for (int u = tid; u < M1 * HS; u += 256) {
        int rr = u >> 7, x = u & 127;
        int s0, s1;
        oa_range(x, s0, s1);
        const float* dr = dpl + rr * M1;
        float a = 0.f;
        for (int ss = s0; ss <= s1; ss++) a += dr[ss];
        trow[rr * HS + x] = a;
    }
    __syncthreads();

    float* dst = out + (size_t)bkc * (HS * HS);
    for (int u = tid; u < HS * HS; u += 256) {
        int y = u >> 7, x = u & 127;
        int r0, r1;
        oa_range(y, r0, r1);
        float a = 0.f;
        for (int rr = r0; rr <= r1; rr++) a += trow[rr * HS + x];
        dst[u] = a;
    }
}

// fused, 512 threads: blocks [0,640) = diff planes; rest = score chunks
__global__ __launch_bounds__(512) void img_fused_kernel(const float* __restrict__ sv_ws,
                                                        const float* __restrict__ dsum_ws,
                                                        float* __restrict__ out) {
    __shared__ float dpl[NP];
    __shared__ float trow[M1 * HS];
    const int tid = threadIdx.x;
    if (blockIdx.x < B_ * KK * C_) {
        const int bkc = blockIdx.x;
        const float* src = dsum_ws + (size_t)bkc * NP;
        for (int i = tid; i < NP; i += 512) dpl[i] = src[i];
        __syncthreads();
        for (int u = tid; u < M1 * HS; u += 512) {
            int rr = u >> 7, x = u & 127;
            int s0, s1;
            oa_range(x, s0, s1);
            const float* dr = dpl + rr * M1;
            float a = 0.f;
            for (int ss = s0; ss <= s1; ss++) a += dr[ss];
            trow[rr * HS + x] = a;
        }
        __syncthreads();
        float* dst = out + OUT_DIFF_OFF + (size_t)bkc * (HS * HS);
        for (int u = tid; u < HS * HS; u += 512) {
            int y = u >> 7, x = u & 127;
            int r0, r1;
            oa_range(y, r0, r1);
            float a = 0.f;
            for (int rr = r0; rr <= r1; rr++) a += trow[rr * HS + x];
            dst[u] = a;
        }
    } else {
        int idx = (blockIdx.x - B_ * KK * C_) * 512 + tid;
        if (idx >= OUT_SCORE_SZ) return;
        int x = idx & 127, y = (idx >> 7) & 127;
        int bk = idx >> 14;
        int r0, r1, s0, s1;
        oa_range(y, r0, r1);
        oa_range(x, s0, s1);
        const float* base = sv_ws + bk * NP;
        float acc = 0.f;
        for (int rr = r0; rr <= r1; rr++)
            for (int ss = s0; ss <= s1; ss++)
                acc += base[rr * M1 + ss];
        out[idx] = acc;
    }
}

extern "C" void kernel_launch(void* const* d_in, const int* in_sizes, int n_in,
                              void* d_out, int out_size, void* d_ws, size_t ws_size,
                              hipStream_t stream) {
    const float* xe = (const float*)d_in[0];
    const float* ye = (const float*)d_in[1];
    float* out = (float*)d_out;
    float* ws = (float*)d_ws;

    float* xnp = ws + WS_XNP;
    float* ynp = ws + WS_YNP;
    int*   topw = (int*)(ws + WS_TOP);
    float* sv_ws = ws + WS_SV;
    float* dsum_ws = ws + WS_DSUM;
    float* xpm = ws + WS_XPM;
    float* ypm = ws + WS_YPM;
    unsigned int* ypbfW = (unsigned int*)(ws + WS_YPBF);
    unsigned int* xebfW = (unsigned int*)(ws + WS_XEBF);

    const bool pm_ok = (ws_size >= WS_NEED_BYTES);
    const int normBlocks = (2 * B_ * NP * 8 + 255) / 256;

    if (pm_ok) {
        prep_fused_kernel<<<B_ * HW + 2 * B_ * M1, 512, 0, stream>>>(xe, ye, xebfW, xpm, ypm, ypbfW);
        norm_np_pm_kernel<<<normBlocks, 256, 0, stream>>>(xpm, ypm, xnp, ynp);
        gemm32_kernel<<<B_ * 128, 1024, 0, stream>>>((const unsigned short*)ypbfW,
                                                     (const unsigned short*)xebfW, xnp, topw);
        emu_pm_kernel<<<B_ * NP, 256, 0, stream>>>(xpm, ypm, xnp, ynp, topw,
                                                   out + OUT_IDX_OFF, sv_ws, dsum_ws);
        img_fused_kernel<<<B_ * KK * C_ + (OUT_SCORE_SZ + 511) / 512, 512, 0, stream>>>(sv_ws, dsum_ws, out);
    } else {
        norm_np_kernel<<<normBlocks, 256, 0, stream>>>(xe, ye, xnp, ynp);
        gemm_select_fb<<<2 * 256, 1024, 0, stream>>>(xe, ye, xnp, topw);
        emu_fallback_kernel<<<B_ * NP, 256, 0, stream>>>(xe, ye, xnp, ynp, topw,
                                                         out + OUT_IDX_OFF, sv_ws, dsum_ws);
        score_img_kernel<<<OUT_SCORE_SZ / 256, 256, 0, stream>>>(sv_ws, out);
        diff_img_sep_kernel<<<B_ * KK * C_, 256, 0, stream>>>(dsum_ws, out + OUT_DIFF_OFF);
    }
}

// Round 19
// 124.208 us; speedup vs baseline: 1.4441x; 1.0361x over previous
//
#include <hip/hip_runtime.h>
#include <float.h>
#include <math.h>

#define B_ 2
#define C_ 64
#define HW 64
#define M1 62
#define NP (M1*M1)      // 3844
#define WIN 30
#define KK 5
#define NSEL 16
#define HS 128

#define OUT_SCORE_SZ (B_*KK*HS*HS)       // 163840
#define OUT_IDX_OFF  (OUT_SCORE_SZ)
#define OUT_IDX_SZ   (B_*NP*KK)          // 38440
#define OUT_DIFF_OFF (OUT_IDX_OFF+OUT_IDX_SZ)
#define OUT_DIFF_SZ  (B_*KK*C_*HS*HS)    // 10485760

// ws layout in floats
#define WS_XNP 0
#define WS_YNP 8192
#define WS_TOP 16384                      // ints: B_*NP*16 = 123008
#define WS_SV  (16384+123008)             // 139392
#define WS_DSUM (139392+40960)            // 180352
#define WS_XPM  (180352+2460160)          // 2640512
#define XPM_F   (B_*NP*576)               // 4428288 floats
#define WS_YPM  (WS_XPM + XPM_F)          // 7068800
#define WS_YPBF (WS_YPM + XPM_F)          // 11497088 (ushorts: B_*NP*576)
#define WS_XEBF (WS_YPBF + XPM_F/2)       // 13711232 (ushorts: B_*64*64*64)
#define WS_END  (WS_XEBF + 262144)        // 13973376
#define WS_NEED_BYTES ((size_t)WS_END * 4)   // ~55.9 MB

typedef __attribute__((ext_vector_type(8))) short bf16x8;
typedef __attribute__((ext_vector_type(4))) short bf16x4;
typedef __attribute__((ext_vector_type(4))) short s16x4;
typedef __attribute__((ext_vector_type(4))) float f32x4;
typedef __attribute__((ext_vector_type(16))) float f32x16;

__device__ __forceinline__ unsigned short f2bf(float f) {
    union { float f; unsigned int u; } v; v.f = f;
    unsigned int r = (v.u + 0x7FFFu + ((v.u >> 16) & 1u)) >> 16;
    return (unsigned short)r;
}

__device__ __forceinline__ bf16x8 ld_bf8(const short* p) {
    bf16x4 lo = *(const bf16x4*)p;
    bf16x4 hi = *(const bf16x4*)(p + 4);
    bf16x8 r;
    r[0] = lo[0]; r[1] = lo[1]; r[2] = lo[2]; r[3] = lo[3];
    r[4] = hi[0]; r[5] = hi[1]; r[6] = hi[2]; r[7] = hi[3];
    return r;
}

// ---------------- K0: fused prep (xebf + im2patch + np-norms), 512t ---------
__global__ __launch_bounds__(512) void prep_fused_kernel(const float* __restrict__ xe,
                                                         const float* __restrict__ ye,
                                                         unsigned int* __restrict__ xebfW,
                                                         float* __restrict__ xpm,
                                                         float* __restrict__ ypm,
                                                         unsigned int* __restrict__ ypbfW,
                                                         float* __restrict__ xnp,
                                                         float* __restrict__ ynp) {
    __shared__ __align__(16) unsigned char sm[64 * 192 * 4 + 1152 * 4];
    const int tid = threadIdx.x;
    const int bid = blockIdx.x;

    if (bid < B_ * HW) {
        float* tile = (float*)sm;   // 64*65 floats
        int b = bid >> 6, h = bid & 63;
        for (int i = tid; i < 4096; i += 512) {
            int c = i >> 6, w = i & 63;
            tile[c * 65 + w] = xe[(((size_t)b * C_ + c) * HW + h) * HW + w];
        }
        __syncthreads();
        for (int j = tid; j < 2048; j += 512) {
            int w = j >> 5, cp = j & 31;
            unsigned int u = (unsigned int)f2bf(tile[(2 * cp) * 65 + w])
                           | ((unsigned int)f2bf(tile[(2 * cp + 1) * 65 + w]) << 16);
            xebfW[(((size_t)b * HW + h) * HW + w) * 32 + cp] = u;
        }
    } else {
        int bid2 = bid - B_ * HW;
        float* rows = (float*)sm;                     // 64*192
        int* tabL = (int*)(sm + 64 * 192 * 4);
        int* tabP = tabL + 576;
        const int srcI = bid2 / (B_ * M1);
        const int rem = bid2 - srcI * (B_ * M1);
        const int b = rem / M1, r = rem - b * M1;
        const float* src = (srcI ? ye : xe) + (size_t)b * C_ * HW * HW;
        float* dst = (srcI ? ypm : xpm) + (size_t)(b * NP + r * M1) * 576;

        for (int t = tid; t < 576; t += 512) {
            int c = t / 9, p = t - c * 9;
            tabL[t] = c * 192 + (p / 3) * 64 + (p % 3);
            int cj = (t / 144) * 16 + (t & 15), pj = (t % 144) >> 4;
            tabP[t] = cj * 192 + (pj / 3) * 64 + (pj % 3);
        }
        for (int i = tid; i < 64 * 192; i += 512) {
            rows[i] = src[(i / 192) * (HW * HW) + r * HW + (i % 192)];
        }
        __syncthreads();

        // patch copies (+ permuted bf16 y), two s per iteration
        const int sh = tid >> 8;           // 0 or 1
        const int tl = tid & 255;
        for (int s2 = 0; s2 < M1; s2 += 2) {
            int s = s2 + sh;
            float* d = dst + s * 576;
            for (int e = tl; e < 576; e += 256) d[e] = rows[tabL[e] + s];
            if (srcI) {
                unsigned int* yb = ypbfW + (size_t)(b * NP + r * M1 + s) * 288;
                for (int j2 = tl; j2 < 288; j2 += 256) {
                    unsigned int u = (unsigned int)f2bf(rows[tabP[2 * j2] + s])
                                   | ((unsigned int)f2bf(rows[tabP[2 * j2 + 1] + s]) << 16);
                    yb[j2] = u;
                }
            }
        }

        // fused numpy-pairwise norms: 64 patch-slots x 8 leaf lanes.
        // Values rows[tabL[e]+s] are bit-identical to the xpm/ypm copies;
        // leaf (72-elem scalar 8-acc) + xor-tree order matches norm_np_pm.
        {
            const int sp = tid >> 3;       // 0..63
            const int leaf = tid & 7;
            float t = 0.f;
            if (sp < M1) {
                const int base = leaf * 72;
                float a8[8];
                #pragma unroll
                for (int i = 0; i < 8; i++) {
                    float v = rows[tabL[base + i] + sp];
                    a8[i] = v * v;
                }
                for (int i0 = 8; i0 < 72; i0 += 8) {
                    #pragma unroll
                    for (int i = 0; i < 8; i++) {
                        float v = rows[tabL[base + i0 + i] + sp];
                        a8[i] += v * v;
                    }
                }
                t = ((a8[0] + a8[1]) + (a8[2] + a8[3])) + ((a8[4] + a8[5]) + (a8[6] + a8[7]));
            }
            t = t + __shfl_xor(t, 1, 8);
            t = t + __shfl_xor(t, 2, 8);
            t = t + __shfl_xor(t, 4, 8);
            if (sp < M1 && leaf == 0)
                (srcI ? ynp : xnp)[b * NP + r * M1 + sp] = t;
        }
    }
}

// ---------------- K1b: fallback norms (scattered) ---------------------------
__global__ __launch_bounds__(256) void norm_np_kernel(const float* __restrict__ xe,
                                                      const float* __restrict__ ye,
                                                      float* __restrict__ xnp,
                                                      float* __restrict__ ynp) {
    __shared__ int tab[576];
    for (int t = threadIdx.x; t < 576; t += 256) {
        int c = t / 9, p = t - c * 9;
        tab[t] = c * (HW * HW) + (p / 3) * HW + (p % 3);
    }
    __syncthreads();

    int gid = blockIdx.x * 256 + threadIdx.x;
    if (gid >= 2 * B_ * NP * 8) return;
    int which = gid / (B_ * NP * 8);
    int rem = gid - which * (B_ * NP * 8);
    int patch = rem >> 3, leaf = rem & 7;
    int b = patch / NP, m = patch - b * NP;
    int r = m / M1, s = m - r * M1;
    const float* src = (which ? ye : xe) + (size_t)b * C_ * HW * HW + r * HW + s;

    int base = leaf * 72;
    float a8[8];
    #pragma unroll
    for (int i = 0; i < 8; i++) { float v = src[tab[base + i]]; a8[i] = v * v; }
    for (int i0 = 8; i0 < 72; i0 += 8) {
        #pragma unroll
        for (int i = 0; i < 8; i++) { float v = src[tab[base + i0 + i]]; a8[i] += v * v; }
    }
    float t = ((a8[0] + a8[1]) + (a8[2] + a8[3])) + ((a8[4] + a8[5]) + (a8[6] + a8[7]));
    t = t + __shfl_xor(t, 1, 8);
    t = t + __shfl_xor(t, 2, 8);
    t = t + __shfl_xor(t, 4, 8);
    if (leaf == 0) (which ? ynp : xnp)[patch] = t;
}

// ---------------- K2: 32x32 MFMA prescreen -----------------------------------
#define UROW 39
#define UCOL 35
#define PSTR 24
#define QSTR 584
#define G_YOFF (UROW*UCOL*PSTR*2)
#define G_XNOFF (G_YOFF + 32*QSTR*2)
#define G_SM (G_XNOFF + 1280*4)

__global__ __launch_bounds__(1024, 4) void gemm32_kernel(const unsigned short* __restrict__ ypbf,
                                                         const unsigned short* __restrict__ xebf,
                                                         const float* __restrict__ xnp,
                                                         int* __restrict__ top_ws) {
    __shared__ __align__(16) unsigned char smem[G_SM];
    short* xs = (short*)smem;
    short* ysS = (short*)(smem + G_YOFF);
    float* xnL = (float*)(smem + G_XNOFF);
    unsigned int* DlU = (unsigned int*)smem;

    const int bid = blockIdx.x;
    const int b = bid >> 7;
    const int t = bid & 127;
    const int r0 = (t >> 4) * 8;
    const int s0 = (t & 15) * 4;
    const int u0r = min(max(r0 - 15, 0), 32);
    const int u0c = min(max(s0 - 15, 0), 32);
    const int tid = threadIdx.x;
    const int l = tid & 63;
    const int w = tid >> 6;
    const int lq = l & 31;
    const int kh = l >> 5;

    for (int u = tid; u < 32 * 144; u += 1024) {
        int q = u / 144, j4 = u - q * 144;
        int rq = min(r0 + (q >> 2), 61), sq = min(s0 + (q & 3), 61);
        s16x4 v = *(const s16x4*)(ypbf + (size_t)(b * NP + rq * M1 + sq) * 576 + j4 * 4);
        *(s16x4*)(ysS + q * QSTR + j4 * 4) = v;
    }
    for (int i = tid; i < 1221; i += 1024) {
        int cr = i / 33, cc = i - cr * 33;
        int nr = min(u0r + cr, 61), nc = min(u0c + cc, 61);
        xnL[i] = xnp[b * NP + nr * M1 + nc];
    }

    int crA[3], ccA[3];
    #pragma unroll
    for (int t3 = 0; t3 < 3; t3++) {
        int tile = t3 * 16 + w;
        int ci = min(tile * 32 + lq, 1220);
        int cr = ci / 33;
        crA[t3] = cr;
        ccA[t3] = ci - cr * 33;
    }
    const bool v2 = (w < 7);

    f32x16 acc0 = {}, acc1 = {}, acc2 = {};

    for (int chunk = 0; chunk < 4; chunk++) {
        __syncthreads();
        for (int u = tid; u < UROW * UCOL; u += 1024) {
            int rr = u / UCOL, c2 = u - rr * UCOL;
            int gr = min(u0r + rr, 63), gc = min(u0c + c2, 63);
            const unsigned short* sp = xebf + ((((size_t)b * HW + gr) * HW + gc) << 6) + chunk * 16;
            int4 v0 = *(const int4*)sp;
            int4 v1 = *(const int4*)(sp + 8);
            *(int4*)(xs + u * PSTR) = v0;
            *(int4*)(xs + u * PSTR + 8) = v1;
        }
        __syncthreads();

        #pragma unroll
        for (int p = 0; p < 9; p++) {
            const int pi = p / 3, pj = p % 3;
            bf16x8 af = *(const bf16x8*)(ysS + lq * QSTR + chunk * 144 + p * 16 + kh * 8);
            {
                const short* bp = xs + ((crA[0] + pi) * UCOL + (ccA[0] + pj)) * PSTR + kh * 8;
                acc0 = __builtin_amdgcn_mfma_f32_32x32x16_bf16(af, *(const bf16x8*)bp, acc0, 0, 0, 0);
            }
            {
                const short* bp = xs + ((crA[1] + pi) * UCOL + (ccA[1] + pj)) * PSTR + kh * 8;
                acc1 = __builtin_amdgcn_mfma_f32_32x32x16_bf16(af, *(const bf16x8*)bp, acc1, 0, 0, 0);
            }
            if (v2) {
                const short* bp = xs + ((crA[2] + pi) * UCOL + (ccA[2] + pj)) * PSTR + kh * 8;
                acc2 = __builtin_amdgcn_mfma_f32_32x32x16_bf16(af, *(const bf16x8*)bp, acc2, 0, 0, 0);
            }
        }
    }

    for (int ph = 0; ph < 2; ph++) {
        __syncthreads();
        #pragma unroll
        for (int t3 = 0; t3 < 3; t3++) {
            if (t3 == 2 && !v2) continue;
            int ci = (t3 * 16 + w) * 32 + lq;
            if (ci <= 1220) {
                float xnv = xnL[ci];
                #pragma unroll
                for (int j = 0; j < 8; j++) {
                    int jj = ph * 8 + j;
                    float av = (t3 == 0) ? acc0[jj] : (t3 == 1 ? acc1[jj] : acc2[jj]);
                    int row = (jj & 3) + 8 * (jj >> 2) + 4 * kh;
                    float v = xnv - 2.0f * av;
                    unsigned int u = __float_as_uint(v);
                    u ^= (unsigned int)((int)u >> 31) | 0x80000000u;
                    DlU[(row - ph * 16) * 1280 + ci] = (u & 0xFFFFF800u) | (unsigned int)ci;
                }
            }
        }
        __syncthreads();
        {
            int q = ph * 16 + w;
            int rq = r0 + (q >> 2), sq = s0 + (q & 3);
            if (rq <= 61 && sq <= 61) {
                int siq = min(max(rq - 15, 0), 32);
                int sjq = min(max(sq - 15, 0), 32);
                int ro = siq - u0r, co = sjq - u0c;
                unsigned int* Dq = DlU + w * 1280;
                const int active = (l < 60);
                const int wi2 = l >> 1, wj0 = (l & 1) * 15;
                const int cbase = (ro + wi2) * 33 + (co + wj0);
                unsigned int myMin = 0xFFFFFFFFu;
                if (active) {
                    #pragma unroll
                    for (int kk = 0; kk < 15; kk++) myMin = min(myMin, Dq[cbase + kk]);
                }
                int obase = (b * NP + rq * M1 + sq) * NSEL;
                for (int it = 0; it < NSEL; it++) {
                    unsigned int lm = myMin;
                    #pragma unroll
                    for (int off = 32; off >= 1; off >>= 1)
                        lm = min(lm, (unsigned int)__shfl_xor((int)lm, off));
                    if (l == 0) {
                        int ci = (int)(lm & 2047u);
                        int cr = ci / 33, cc = ci - (ci / 33) * 33;
                        top_ws[obase + it] = (u0r + cr) * M1 + (u0c + cc);
                    }
                    if (active && myMin == lm) {
                        int wk = (int)(lm & 2047u) - cbase;
                        Dq[cbase + wk] = 0xFFFFFFFFu;
                        myMin = 0xFFFFFFFFu;
                        #pragma unroll
                        for (int kk = 0; kk < 15; kk++) myMin = min(myMin, Dq[cbase + kk]);
                    }
                }
            }
        }
    }
}

// ---------------- K2-fb: old 16x16 prescreen (scattered staging) ------------
#define UPC2 40
#define CSTR2 20
#define YSTR2 580
#define ZOFF_SH (16*YSTR2)
#define YS2_OFF 56000
#define XN2_OFF (YS2_OFF + (ZOFF_SH+16)*2)
#define SM2_BYTES (XN2_OFF + 1089*4)

__global__ __launch_bounds__(1024, 4) void gemm_select_fb(const float* __restrict__ xe,
                                                          const float* __restrict__ ye,
                                                          const float* __restrict__ xnp,
                                                          int* __restrict__ top_ws) {
    __shared__ __align__(16) unsigned char smem[SM2_BYTES];
    short* xsS = (short*)smem;
    unsigned int* xsW = (unsigned int*)smem;
    short* ysS = (short*)(smem + YS2_OFF);
    float* xnL = (float*)(smem + XN2_OFF);
    unsigned int* DlU = (unsigned int*)smem;

    const int bid = blockIdx.x;
    const int b  = bid >> 8;
    const int t  = bid & 255;
    const int r0 = (t >> 4) * 4;
    const int s0 = (t & 15) * 4;
    const int u0r = min(max(r0 - 15, 0), 32);
    const int u0c = min(max(s0 - 15, 0), 32);
    const int g0c = min(u0c & ~3, 24);
    const int cofs = u0c - g0c;
    const int tid = threadIdx.x;
    const int l   = tid & 63;
    const int wid = tid >> 6;
    const int lq  = l & 15;
    const int kg  = l >> 4;
    const int kgh = kg >> 1, kgl = kg & 1;

    for (int u = tid; u < 16 * 576; u += 1024) {
        int q = u / 576, e = u - q * 576;
        int rq = min(r0 + (q >> 2), 61), sq = min(s0 + (q & 3), 61);
        int c = e / 9, p = e - c * 9;
        float v = ye[((b * C_ + c) * HW + rq + p / 3) * HW + sq + p % 3];
        ysS[q * YSTR2 + (c >> 4) * 144 + p * 16 + (c & 15)] = (short)f2bf(v);
    }
    if (tid < 16) ysS[ZOFF_SH + tid] = 0;
    for (int i = tid; i < 1089; i += 1024) {
        int cr = i / 33, cc = i - cr * 33;
        int nr = min(u0r + cr, 61), nc = min(u0c + cc, 61);
        xnL[i] = xnp[b * NP + nr * M1 + nc];
    }

    f32x4 acc[5];
    #pragma unroll
    for (int i = 0; i < 5; i++) acc[i] = (f32x4){0.f, 0.f, 0.f, 0.f};

    const int PI0[4] = {0, 0, 1, 2}, PJ0[4] = {0, 2, 1, 0};
    const int PI1[4] = {0, 1, 1, 2}, PJ1[4] = {1, 0, 2, 1};

    int prb[5], pcb[5];
    #pragma unroll
    for (int i = 0; i < 5; i++) {
        int ci = (wid * 5 + i) * 16 + lq;
        int cis = min(ci, 1088);
        int cr = cis / 33;
        prb[i] = cr;
        pcb[i] = cis - cr * 33 + cofs;
    }

    for (int chunk = 0; chunk < 4; chunk++) {
        __syncthreads();
        for (int u = tid; u < 560; u += 1024) {
            int cp = u & 7, rh = u >> 3;
            int row = rh % 35, half = rh / 35;
            int c0 = chunk * 16 + cp * 2;
            int gr = min(u0r + row, 63);
            const float4* pa = (const float4*)(xe + ((size_t)(b * C_ + c0) * HW + gr) * HW + g0c);
            const float4* pb = (const float4*)(xe + ((size_t)(b * C_ + c0 + 1) * HW + gr) * HW + g0c);
            #pragma unroll
            for (int bb = 0; bb < 5; bb++) {
                int blk = half * 5 + bb;
                float4 va = pa[blk], vb = pb[blk];
                int w0 = (row * UPC2 + blk * 4) * (CSTR2 / 2) + cp;
                xsW[w0     ] = (unsigned)f2bf(va.x) | ((unsigned)f2bf(vb.x) << 16);
                xsW[w0 + 10] = (unsigned)f2bf(va.y) | ((unsigned)f2bf(vb.y) << 16);
                xsW[w0 + 20] = (unsigned)f2bf(va.z) | ((unsigned)f2bf(vb.z) << 16);
                xsW[w0 + 30] = (unsigned)f2bf(va.w) | ((unsigned)f2bf(vb.w) << 16);
            }
        }
        __syncthreads();

        const int aBase = lq * YSTR2 + chunk * 144;
        #pragma unroll
        for (int t4 = 0; t4 < 5; t4++) {
            bf16x8 af;
            int pi, pj;
            if (t4 < 4) {
                int p = 2 * t4 + kgh;
                af = ld_bf8(ysS + aBase + p * 16 + kgl * 8);
                pi = kgh ? PI1[t4] : PI0[t4];
                pj = kgh ? PJ1[t4] : PJ0[t4];
            } else {
                af = ld_bf8(ysS + ((kg < 2) ? (aBase + 8 * 16 + kgl * 8) : (ZOFF_SH + kgl * 8)));
                pi = 2; pj = 2;
            }
            #pragma unroll
            for (int i = 0; i < 5; i++) {
                bf16x8 bf = ld_bf8(xsS + ((prb[i] + pi) * UPC2 + (pcb[i] + pj)) * CSTR2 + kgl * 8);
                acc[i] = __builtin_amdgcn_mfma_f32_16x16x32_bf16(af, bf, acc[i], 0, 0, 0);
            }
        }
    }

    __syncthreads();
    #pragma unroll
    for (int i = 0; i < 5; i++) {
        int ci = (wid * 5 + i) * 16 + lq;
        if (ci < 1089) {
            float xnv = xnL[ci];
            #pragma unroll
            for (int j = 0; j < 4; j++) {
                float v = xnv - 2.0f * acc[i][j];
                unsigned int u = __float_as_uint(v);
                u ^= (unsigned int)((int)u >> 31) | 0x80000000u;
                DlU[(kg * 4 + j) * 1089 + ci] = (u & 0xFFFFF800u) | (unsigned int)ci;
            }
        }
    }
    __syncthreads();

    {
        int q = wid;
        int rq = r0 + (q >> 2), sq = s0 + (q & 3);
        if (rq <= 61 && sq <= 61) {
            int siq = min(max(rq - 15, 0), 32);
            int sjq = min(max(sq - 15, 0), 32);
            int ro = siq - u0r, co = sjq - u0c;
            unsigned int* Dq = DlU + q * 1089;
            const int active = (l < 60);
            const int wi2 = l >> 1, wj0 = (l & 1) * 15;
            const int cbase = (ro + wi2) * 33 + (co + wj0);
            unsigned int myMin = 0xFFFFFFFFu;
            if (active) {
                #pragma unroll
                for (int kk = 0; kk < 15; kk++) myMin = min(myMin, Dq[cbase + kk]);
            }
            int obase = (b * NP + rq * M1 + sq) * NSEL;
            for (int it = 0; it < NSEL; it++) {
                unsigned int lm = myMin;
                #pragma unroll
                for (int off = 32; off >= 1; off >>= 1)
                    lm = min(lm, (unsigned int)__shfl_xor((int)lm, off));
                if (l == 0) {
                    int ci = (int)(lm & 2047u);
                    int cr = ci / 33, cc = ci - (ci / 33) * 33;
                    top_ws[obase + it] = (u0r + cr) * M1 + (u0c + cc);
                }
                if (active && myMin == lm) {
                    int wk = (int)(lm & 2047u) - cbase;
                    Dq[cbase + wk] = 0xFFFFFFFFu;
                    myMin = 0xFFFFFFFFu;
                    #pragma unroll
                    for (int kk = 0; kk < 15; kk++) myMin = min(myMin, Dq[cbase + kk]);
                }
            }
        }
    }
}

// ---------------- K3a: emu from patch-major buffers (dense reads) -----------
__global__ __launch_bounds__(256) void emu_pm_kernel(const float* __restrict__ xpm,
                                                     const float* __restrict__ ypm,
                                                     const float* __restrict__ xnp,
                                                     const float* __restrict__ ynp,
                                                     const int* __restrict__ top_ws,
                                                     float* __restrict__ out_idx,
                                                     float* __restrict__ sv_ws,
                                                     float* __restrict__ dsum_ws) {
    __shared__ float ysE[576];
    __shared__ int topWs[NSEL];
    __shared__ float keyEmu[NSEL];
    __shared__ float selKey[KK];
    __shared__ int   selN[KK];

    const int bid0 = blockIdx.x;
    const int bid = (bid0 & 7) * (B_ * NP / 8) + (bid0 >> 3);  // XCD-affine
    const int b = bid / NP, m = bid - b * NP;
    const int tid = threadIdx.x;
    const float* ybase = ypm + (size_t)(b * NP + m) * 576;

    for (int t = tid; t < 576; t += 256) ysE[t] = ybase[t];
    if (tid < NSEL) topWs[tid] = top_ws[bid * NSEL + tid];
    __syncthreads();

    {
        const int cand = tid >> 4, j = tid & 15;
        const float* xp = xpm + (size_t)(b * NP + topWs[cand]) * 576;
        float acc = 0.f;
        #pragma unroll
        for (int t = 0; t < 36; t++) {
            int e = t * 16 + j;
            acc = fmaf(ysE[e], xp[e], acc);
        }
        float E = acc;
        E = E + __shfl_xor(E, 8, 16);
        E = E + __shfl_xor(E, 4, 16);
        E = E + __shfl_xor(E, 2, 16);
        E = E + __shfl_xor(E, 1, 16);
        if (j == 0) {
            float t0 = -2.0f * E;
            float k1 = t0 + ynp[b * NP + m];
            float k2 = k1 + xnp[b * NP + topWs[cand]];
            keyEmu[cand] = k2 + 1e-5f;
        }
    }
    __syncthreads();

    if (tid == 0) {
        float d[NSEL]; int w[NSEL];
        for (int i = 0; i < NSEL; i++) { d[i] = keyEmu[i]; w[i] = topWs[i]; }
        for (int a = 1; a < NSEL; a++) {
            float dv = d[a]; int wv2 = w[a]; int p = a - 1;
            while (p >= 0 && (d[p] > dv || (d[p] == dv && w[p] > wv2))) {
                d[p + 1] = d[p]; w[p + 1] = w[p]; p--;
            }
            d[p + 1] = dv; w[p + 1] = wv2;
        }
        for (int i = 0; i < KK; i++) { selKey[i] = d[i]; selN[i] = w[i]; }
    }
    __syncthreads();

    if (tid < KK) {
        out_idx[(b * NP + m) * KK + tid] = (float)selN[tid];
        float s10 = selKey[tid] / 10.0f;
        double sv = exp(-(double)s10);
        sv_ws[(b * KK + tid) * NP + m] = (float)sv;
    }

    for (int pair = tid; pair < KK * C_; pair += 256) {
        int k = pair >> 6, c = pair & 63;
        const float* xrow = xpm + (size_t)(b * NP + selN[k]) * 576 + c * 9;
        const float* yrow = ysE + c * 9;
        float a = 0.f;
        #pragma unroll
        for (int p = 0; p < 9; p++) a += fabsf(yrow[p] - xrow[p]);
        dsum_ws[((b * KK + k) * C_ + c) * NP + m] = a;
    }
}

// ---------------- K3b: fallback emu (scattered) ------------------------------
#define XCSTR 584

__global__ __launch_bounds__(256) void emu_fallback_kernel(const float* __restrict__ xe,
                                                           const float* __restrict__ ye,
                                                           const float* __restrict__ xnp,
                                                           const float* __restrict__ ynp,
                                                           const int* __restrict__ top_ws,
                                                           float* __restrict__ out_idx,
                                                           float* __restrict__ sv_ws,
                                                           float* __restrict__ dsum_ws) {
    __shared__ float ysE[576];
    __shared__ int tab[576];
    __shared__ float xc[NSEL * XCSTR];
    __shared__ int topWs[NSEL];
    __shared__ float keyEmu[NSEL];
    __shared__ float selKey[KK];
    __shared__ int   selN[KK];
    __shared__ int   selI[KK];

    const int bid0 = blockIdx.x;
    const int bid = (bid0 & 7) * (B_ * NP / 8) + (bid0 >> 3);
    const int b = bid / NP, m = bid - b * NP;
    const int r = m / M1, s = m - r * M1;
    const int tid = threadIdx.x;
    const float* xb = xe + (size_t)b * C_ * HW * HW;
    const float* yb = ye + (size_t)b * C_ * HW * HW + r * HW + s;

    for (int t = tid; t < 576; t += 256) {
        int c = t / 9, p = t - c * 9;
        tab[t] = c * (HW * HW) + (p / 3) * HW + (p % 3);
    }
    if (tid < NSEL) topWs[tid] = top_ws[bid * NSEL + tid];
    __syncthreads();

    for (int t = tid; t < 576; t += 256) ysE[t] = yb[tab[t]];
    for (int i = tid; i < NSEL * 576; i += 256) {
        int cand = i / 576, e = i - cand * 576;
        int n = topWs[cand];
        int px = n / M1, py = n - px * M1;
        xc[cand * XCSTR + e] = xb[px * HW + py + tab[e]];
    }
    __syncthreads();

    {
        const int cand = tid >> 4, j = tid & 15;
        const float* xcp = xc + cand * XCSTR;
        float acc = 0.f;
        #pragma unroll
        for (int t = 0; t < 36; t++) {
            int e = t * 16 + j;
            acc = fmaf(ysE[e], xcp[e], acc);
        }
        float E = acc;
        E = E + __shfl_xor(E, 8, 16);
        E = E + __shfl_xor(E, 4, 16);
        E = E + __shfl_xor(E, 2, 16);
        E = E + __shfl_xor(E, 1, 16);
        if (j == 0) {
            float t0 = -2.0f * E;
            float k1 = t0 + ynp[b * NP + m];
            float k2 = k1 + xnp[b * NP + topWs[cand]];
            keyEmu[cand] = k2 + 1e-5f;
        }
    }
    __syncthreads();

    if (tid == 0) {
        float d[NSEL]; int w[NSEL]; int ix[NSEL];
        for (int i = 0; i < NSEL; i++) { d[i] = keyEmu[i]; w[i] = topWs[i]; ix[i] = i; }
        for (int a = 1; a < NSEL; a++) {
            float dv = d[a]; int wv2 = w[a]; int iv = ix[a]; int p = a - 1;
            while (p >= 0 && (d[p] > dv || (d[p] == dv && w[p] > wv2))) {
                d[p + 1] = d[p]; w[p + 1] = w[p]; ix[p + 1] = ix[p]; p--;
            }
            d[p + 1] = dv; w[p + 1] = wv2; ix[p + 1] = iv;
        }
        for (int i = 0; i < KK; i++) { selKey[i] = d[i]; selN[i] = w[i]; selI[i] = ix[i]; }
    }
    __syncthreads();

    if (tid < KK) {
        out_idx[(b * NP + m) * KK + tid] = (float)selN[tid];
        float s10 = selKey[tid] / 10.0f;
        double sv = exp(-(double)s10);
        sv_ws[(b * KK + tid) * NP + m] = (float)sv;
    }

    for (int pair = tid; pair < KK * C_; pair += 256) {
        int k = pair >> 6, c = pair & 63;
        const float* xcp = xc + selI[k] * XCSTR + c * 9;
        const float* ycp = ysE + c * 9;
        float a = 0.f;
        #pragma unroll
        for (int p = 0; p < 9; p++) a += fabsf(ycp[p] - xcp[p]);
        dsum_ws[((b * KK + k) * C_ + c) * NP + m] = a;
    }
}

// ---------------- overlap-add image kernels ---------------------------------
__device__ __forceinline__ void oa_range(int y, int& r0, int& r1) {
    r0 = (y >= 5) ? ((y - 4) >> 1) : 0;
    r1 = min(M1 - 1, y >> 1);
}

__global__ __launch_bounds__(256) void score_img_kernel(const float* __restrict__ sv_ws,
                                                        float* __restrict__ out) {
    int idx = blockIdx.x * 256 + threadIdx.x;
    if (idx >= OUT_SCORE_SZ) return;
    int x = idx & 127, y = (idx >> 7) & 127;
    int bk = idx >> 14;
    int r0, r1, s0, s1;
    oa_range(y, r0, r1);
    oa_range(x, s0, s1);
    const float* base = sv_ws + bk * NP;
    float acc = 0.f;
    for (int rr = r0; rr <= r1; rr++)
        for (int ss = s0; ss <= s1; ss++)
            acc += base[rr * M1 + ss];
    out[idx] = acc;
}

__global__ __launch_bounds__(256) void diff_img_sep_kernel(const float* __restrict__ dsum_ws,
                                                           float* __restrict__ out) {
    __shared__ float dpl[NP];
    __shared__ float trow[M1 * HS];
    const int bkc = blockIdx.x;
    const int tid = threadIdx.x;
    const float* src = dsum_ws + (size_t)bkc * NP;

    for (int i = tid; i < NP; i += 256) dpl[i] = src[i];
    __syncthreads();

    for (int u = tid; u < M1 * HS; u += 256) {
        int rr = u >> 7, x = u & 127;
        int s0, s1;
        oa_range(x, s0, s1);
        const float* dr = dpl + rr * M1;
        float a = 0.f;
        for (int ss = s0; ss <= s1; ss++) a += dr[ss];
        trow[rr * HS + x] = a;
    }
    __syncthreads();

    float* dst = out + (size_t)bkc * (HS * HS);
    for (int u = tid; u < HS * HS; u += 256) {
        int y = u >> 7, x = u & 127;
        int r0, r1;
        oa_range(y, r0, r1);
        float a = 0.f;
        for (int rr = r0; rr <= r1; rr++) a += trow[rr * HS + x];
        dst[u] = a;
    }
}

// fused, 512 threads: blocks [0,640) = diff planes; rest = score chunks
__global__ __launch_bounds__(512) void img_fused_kernel(const float* __restrict__ sv_ws,
                                                        const float* __restrict__ dsum_ws,
                                                        float* __restrict__ out) {
    __shared__ float dpl[NP];
    __shared__ float trow[M1 * HS];
    const int tid = threadIdx.x;
    if (blockIdx.x < B_ * KK * C_) {
        const int bkc = blockIdx.x;
        const float* src = dsum_ws + (size_t)bkc * NP;
        for (int i = tid; i < NP; i += 512) dpl[i] = src[i];
        __syncthreads();
        for (int u = tid; u < M1 * HS; u += 512) {
            int rr = u >> 7, x = u & 127;
            int s0, s1;
            oa_range(x, s0, s1);
            const float* dr = dpl + rr * M1;
            float a = 0.f;
            for (int ss = s0; ss <= s1; ss++) a += dr[ss];
            trow[rr * HS + x] = a;
        }
        __syncthreads();
        float* dst = out + OUT_DIFF_OFF + (size_t)bkc * (HS * HS);
        for (int u = tid; u < HS * HS; u += 512) {
            int y = u >> 7, x = u & 127;
            int r0, r1;
            oa_range(y, r0, r1);
            float a = 0.f;
            for (int rr = r0; rr <= r1; rr++) a += trow[rr * HS + x];
            dst[u] = a;
        }
    } else {
        int idx = (blockIdx.x - B_ * KK * C_) * 512 + tid;
        if (idx >= OUT_SCORE_SZ) return;
        int x = idx & 127, y = (idx >> 7) & 127;
        int bk = idx >> 14;
        int r0, r1, s0, s1;
        oa_range(y, r0, r1);
        oa_range(x, s0, s1);
        const float* base = sv_ws + bk * NP;
        float acc = 0.f;
        for (int rr = r0; rr <= r1; rr++)
            for (int ss = s0; ss <= s1; ss++)
                acc += base[rr * M1 + ss];
        out[idx] = acc;
    }
}

extern "C" void kernel_launch(void* const* d_in, const int* in_sizes, int n_in,
                              void* d_out, int out_size, void* d_ws, size_t ws_size,
                              hipStream_t stream) {
    const float* xe = (const float*)d_in[0];
    const float* ye = (const float*)d_in[1];
    float* out = (float*)d_out;
    float* ws = (float*)d_ws;

    float* xnp = ws + WS_XNP;
    float* ynp = ws + WS_YNP;
    int*   topw = (int*)(ws + WS_TOP);
    float* sv_ws = ws + WS_SV;
    float* dsum_ws = ws + WS_DSUM;
    float* xpm = ws + WS_XPM;
    float* ypm = ws + WS_YPM;
    unsigned int* ypbfW = (unsigned int*)(ws + WS_YPBF);
    unsigned int* xebfW = (unsigned int*)(ws + WS_XEBF);

    const bool pm_ok = (ws_size >= WS_NEED_BYTES);
    const int normBlocks = (2 * B_ * NP * 8 + 255) / 256;

    if (pm_ok) {
        prep_fused_kernel<<<B_ * HW + 2 * B_ * M1, 512, 0, stream>>>(xe, ye, xebfW, xpm, ypm,
                                                                     ypbfW, xnp, ynp);
        gemm32_kernel<<<B_ * 128, 1024, 0, stream>>>((const unsigned short*)ypbfW,
                                                     (const unsigned short*)xebfW, xnp, topw);
        emu_pm_kernel<<<B_ * NP, 256, 0, stream>>>(xpm, ypm, xnp, ynp, topw,
                                                   out + OUT_IDX_OFF, sv_ws, dsum_ws);
        img_fused_kernel<<<B_ * KK * C_ + (OUT_SCORE_SZ + 511) / 512, 512, 0, stream>>>(sv_ws, dsum_ws, out);
    } else {
        norm_np_kernel<<<normBlocks, 256, 0, stream>>>(xe, ye, xnp, ynp);
        gemm_select_fb<<<2 * 256, 1024, 0, stream>>>(xe, ye, xnp, topw);
        emu_fallback_kernel<<<B_ * NP, 256, 0, stream>>>(xe, ye, xnp, ynp, topw,
                                                         out + OUT_IDX_OFF, sv_ws, dsum_ws);
        score_img_kernel<<<OUT_SCORE_SZ / 256, 256, 0, stream>>>(sv_ws, out);
        diff_img_sep_kernel<<<B_ * KK * C_, 256, 0, stream>>>(dsum_ws, out + OUT_DIFF_OFF);
    }
}